// Round 1
// baseline (177.009 us; speedup 1.0000x reference)
//
#include <hip/hip_runtime.h>
#include <math.h>

#define BB   1024
#define HH   256
#define NN   128
#define SS   2
#define LOG2PI_F 1.8378770664093453f
#define DEV_MIN_F 0.001f
#define DEV_STEP_F 7.08661417322835e-05f   // (0.01-0.001)/127
#define LOG1P_HALF 0.40546510810816438f    // log1p(0.5)

// ---------------------------------------------------------------------------
// GEMM: Y(1024x256) = act(X(1024x256) @ W(256x256) + bias)
// MU variant: W is Wp (N=128, H=256, 2) gathered as Wmat[k][j] = Wp[j>>1][k][j&1],
//             bias = 0.5 + bp[j], no relu.
// Tile 32x32, K-chunk 32, 256 threads, 2x2 micro-tile. Grid (32, 8) = 256 blocks.
// ---------------------------------------------------------------------------
template <bool MU, bool RELU>
__global__ __launch_bounds__(256) void gemm_kernel(const float* __restrict__ X,
                                                   const float* __restrict__ W,
                                                   const float* __restrict__ bias,
                                                   float* __restrict__ Y) {
    // stride 34 (even): float2-aligned reads, 2-way bank alias only (free)
    __shared__ __align__(16) float AsT[32][34];  // AsT[k][row]
    __shared__ __align__(16) float Bs[32][34];   // Bs[k][col]
    const int t  = threadIdx.x;
    const int bm = blockIdx.x * 32;
    const int bn = blockIdx.y * 32;
    const int tx = t & 15, ty = t >> 4;

    float acc00 = 0.f, acc01 = 0.f, acc10 = 0.f, acc11 = 0.f;

    for (int k0 = 0; k0 < 256; k0 += 32) {
        #pragma unroll
        for (int r = 0; r < 4; ++r) {
            int idx = t + r * 256;
            int row = idx >> 5, k = idx & 31;
            AsT[k][row] = X[(bm + row) * 256 + k0 + k];
        }
        #pragma unroll
        for (int r = 0; r < 4; ++r) {
            int idx = t + r * 256;
            int kk = idx >> 5, j = idx & 31;
            float w;
            if (MU) {
                int col = bn + j;
                w = W[(col >> 1) * 512 + (k0 + kk) * 2 + (col & 1)];
            } else {
                w = W[(k0 + kk) * 256 + bn + j];
            }
            Bs[kk][j] = w;
        }
        __syncthreads();
        #pragma unroll
        for (int kk = 0; kk < 32; ++kk) {
            float2 a  = *(const float2*)&AsT[kk][ty * 2];
            float2 bv = *(const float2*)&Bs[kk][tx * 2];
            acc00 = fmaf(a.x, bv.x, acc00);
            acc01 = fmaf(a.x, bv.y, acc01);
            acc10 = fmaf(a.y, bv.x, acc10);
            acc11 = fmaf(a.y, bv.y, acc11);
        }
        __syncthreads();
    }

    const int row0 = bm + ty * 2, col0 = bn + tx * 2;
    float b0 = bias[col0], b1 = bias[col0 + 1];
    if (MU) { b0 += 0.5f; b1 += 0.5f; }
    float v00 = acc00 + b0, v01 = acc01 + b1;
    float v10 = acc10 + b0, v11 = acc11 + b1;
    if (RELU) {
        v00 = fmaxf(v00, 0.f); v01 = fmaxf(v01, 0.f);
        v10 = fmaxf(v10, 0.f); v11 = fmaxf(v11, 0.f);
    }
    Y[row0 * 256 + col0] = v00;
    Y[row0 * 256 + col0 + 1] = v01;
    Y[(row0 + 1) * 256 + col0] = v10;
    Y[(row0 + 1) * 256 + col0 + 1] = v11;
}

// ---------------------------------------------------------------------------
// Fused losses kernel: one block per batch row b, 256 threads, t = n*2 + s.
// Computes sampled, genLoss, realLoss, lossA, lossB.
// Output layout (flat concat, fp32):
//   sampled  (S*N, B, 2) @ 0
//   genLoss  (B, N)      @ 524288
//   realLoss (B, N)      @ 655360
//   lossA    (B, N)      @ 786432
//   lossB    (B, N, S)   @ 917504
// ---------------------------------------------------------------------------
__global__ __launch_bounds__(256) void losses_kernel(
    const float* __restrict__ mu,        // (B, N, 2)
    const float* __restrict__ eps,       // (S, B*N, 2)
    const float* __restrict__ realPts,   // (B, 2)
    const float* __restrict__ predMu,    // (B, 2)
    const float* __restrict__ predScale, // (B, 2)
    float* __restrict__ out) {
    __shared__ float2 smu[NN];   // mu[b, m, :]
    __shared__ float2 sprm[NN];  // (-0.5/dev^2, -2*log(dev) - LOG2PI)

    const int b = blockIdx.x;
    const int t = threadIdx.x;
    const int n = t >> 1;
    const int s = t & 1;

    if (t < NN) {
        smu[t] = ((const float2*)mu)[b * NN + t];
        float dv = DEV_MIN_F + (float)t * DEV_STEP_F;
        sprm[t] = make_float2(-0.5f / (dv * dv), -2.f * __logf(dv) - LOG2PI_F);
    }
    __syncthreads();

    const float devn = DEV_MIN_F + (float)n * DEV_STEP_F;
    const float2 ep  = ((const float2*)eps)[s * (BB * NN) + b * NN + n];
    const float2 mun = smu[n];
    const float px = fmaf(devn, ep.x, mun.x);
    const float py = fmaf(devn, ep.y, mun.y);

    // ---- sampled: [(s*N+n), b, :]  (strided store; 2 MB total) ----
    ((float2*)out)[(s * NN + n) * BB + b] = make_float2(px, py);

    // ---- lossA / genLoss raw logprob under predicted dist (uniform per b) ----
    const float pmx = predMu[b * 2],     pmy = predMu[b * 2 + 1];
    const float psx = predScale[b * 2],  psy = predScale[b * 2 + 1];
    float zx = (px - pmx) / psx, zy = (py - pmy) / psy;
    float la = -0.5f * (zx * zx + zy * zy) - __logf(psx) - __logf(psy) - LOG2PI_F;
    float aa = 1.f / (1.f + __expf(la));    // sigmoid(-la)
    float termA = LOG1P_HALF - log1pf(aa);
    termA = termA * termA;
    float gg = 1.f / (1.f + __expf(-la));   // sigmoid(la)

    // ---- lossB: softmax over 128 modes, two-pass with recompute ----
    float mx = -1e30f;
    #pragma unroll 4
    for (int m = 0; m < NN; ++m) {
        float2 mm = smu[m];
        float2 pr = sprm[m];
        float dx = px - mm.x, dy = py - mm.y;
        float lb = fmaf(fmaf(dx, dx, dy * dy), pr.x, pr.y);
        mx = fmaxf(mx, lb);
    }
    float sum = 0.f, ediag = 0.f;
    #pragma unroll 4
    for (int m = 0; m < NN; ++m) {
        float2 mm = smu[m];
        float2 pr = sprm[m];
        float dx = px - mm.x, dy = py - mm.y;
        float lb = fmaf(fmaf(dx, dx, dy * dy), pr.x, pr.y);
        float e = __expf(lb - mx);
        sum += e;
        if (m == n) ediag = e;
    }
    float diag = ediag / sum;
    float lbv = (1.f - diag) * (1.f - diag);
    out[917504 + b * (NN * SS) + t] = lbv;  // (B, N, S), t == n*2+s

    // ---- realLoss (depends only on (b, n)) ----
    const float rx = realPts[b * 2], ry = realPts[b * 2 + 1];
    float2 prn = sprm[n];
    float drx = rx - mun.x, dry = ry - mun.y;
    float lr = fmaf(fmaf(drx, drx, dry * dry), prn.x, prn.y);
    float rl = 1.f / (1.f + __expf(-lr));

    // ---- reduce over s (adjacent lanes) ----
    float termA_sum = termA + __shfl_xor(termA, 1);
    float gg_sum    = gg + __shfl_xor(gg, 1);
    if (s == 0) {
        out[524288 + b * NN + n] = 0.5f * gg_sum * (1.f - rl);  // genLoss
        out[655360 + b * NN + n] = rl;                          // realLoss
        out[786432 + b * NN + n] = 0.5f * termA_sum;            // lossA
    }
}

// ---------------------------------------------------------------------------
extern "C" void kernel_launch(void* const* d_in, const int* in_sizes, int n_in,
                              void* d_out, int out_size, void* d_ws, size_t ws_size,
                              hipStream_t stream) {
    const float* latents   = (const float*)d_in[0];
    const float* realPts   = (const float*)d_in[1];
    const float* predMu    = (const float*)d_in[2];
    const float* predScale = (const float*)d_in[3];
    const float* eps       = (const float*)d_in[4];
    const float* W0 = (const float*)d_in[5];
    const float* b0 = (const float*)d_in[6];
    const float* W1 = (const float*)d_in[7];
    const float* b1 = (const float*)d_in[8];
    const float* W2 = (const float*)d_in[9];
    const float* b2 = (const float*)d_in[10];
    const float* W3 = (const float*)d_in[11];
    const float* b3 = (const float*)d_in[12];
    const float* W4 = (const float*)d_in[13];
    const float* b4 = (const float*)d_in[14];
    const float* Wp = (const float*)d_in[15];
    const float* bp = (const float*)d_in[16];

    float* h1 = (float*)d_ws;          // 1 MB
    float* h2 = h1 + BB * HH;          // 1 MB

    dim3 ggrid(32, 8), gblock(256);
    // 5-layer relu MLP (ping-pong h1/h2)
    gemm_kernel<false, true><<<ggrid, gblock, 0, stream>>>(latents, W0, b0, h1);
    gemm_kernel<false, true><<<ggrid, gblock, 0, stream>>>(h1, W1, b1, h2);
    gemm_kernel<false, true><<<ggrid, gblock, 0, stream>>>(h2, W2, b2, h1);
    gemm_kernel<false, true><<<ggrid, gblock, 0, stream>>>(h1, W3, b3, h2);
    gemm_kernel<false, true><<<ggrid, gblock, 0, stream>>>(h2, W4, b4, h1);
    // mu projection (gathered Wp) -> h2
    gemm_kernel<true, false><<<ggrid, gblock, 0, stream>>>(h1, Wp, bp, h2);
    // fused losses
    losses_kernel<<<dim3(BB), gblock, 0, stream>>>(h2, eps, realPts, predMu,
                                                   predScale, (float*)d_out);
}

// Round 2
// 175.942 us; speedup vs baseline: 1.0061x; 1.0061x over previous
//
#include <hip/hip_runtime.h>
#include <math.h>

#define BB   1024
#define HH   256
#define NN   128
#define SS   2
#define ROWS 4
#define LOG2PI_F 1.8378770664093453f
#define DEV_MIN_F 0.001f
#define DEV_STEP_F 7.08661417322835e-05f   // (0.01-0.001)/127
#define LOG1P_HALF 0.40546510810816438f    // log1p(0.5)

// Output layout (flat concat, fp32):
//   sampled  (S*N, B, 2) @ 0
//   genLoss  (B, N)      @ 524288
//   realLoss (B, N)      @ 655360
//   lossA    (B, N)      @ 786432
//   lossB    (B, N, S)   @ 917504
#define OFF_GEN  524288
#define OFF_REAL 655360
#define OFF_A    786432
#define OFF_B    917504

// ---------------------------------------------------------------------------
// Pre-transpose Wp (N,H,2) -> Wt[k][j] = Wp[j>>1][k][j&1]  (256x256 row-major)
// so the mu layer reads coalesced like the other layers. Writes coalesced;
// scattered reads are L2-absorbed (Wp = 256 KB).
// ---------------------------------------------------------------------------
__global__ __launch_bounds__(256) void transpose_wp_kernel(
    const float* __restrict__ Wp, float* __restrict__ Wt) {
    const int k = blockIdx.x;
    const int j = threadIdx.x;
    Wt[k * 256 + j] = Wp[(j >> 1) * 512 + k * 2 + (j & 1)];
}

// ---------------------------------------------------------------------------
// Fully fused: 5x relu MLP + mu projection + sampled + all 4 losses.
// Grid 256 blocks x 256 threads; block owns ROWS=4 batch rows.
// MLP: thread j = output column; acc over k with W coalesced from L2,
// h[r][k] broadcast from LDS. Activations never leave LDS.
// ---------------------------------------------------------------------------
__global__ __launch_bounds__(256) void fused_kernel(
    const float* __restrict__ latents,   // (B, 256)
    const float* __restrict__ eps,       // (S, B*N, 2)
    const float* __restrict__ realPts,   // (B, 2)
    const float* __restrict__ predMu,    // (B, 2)
    const float* __restrict__ predScale, // (B, 2)
    const float* __restrict__ W0, const float* __restrict__ b0,
    const float* __restrict__ W1, const float* __restrict__ b1,
    const float* __restrict__ W2, const float* __restrict__ b2,
    const float* __restrict__ W3, const float* __restrict__ b3,
    const float* __restrict__ W4, const float* __restrict__ b4,
    const float* __restrict__ Wt,        // (256, 256) pre-transposed Wp
    const float* __restrict__ bp,        // (N, 2) flat == bias[j]
    float* __restrict__ out) {
    __shared__ float  hbuf[2][ROWS][256];
    __shared__ float2 sprm[NN];          // (-0.5/dev^2, -2*log(dev) - LOG2PI)

    const int t   = threadIdx.x;
    const int brow = blockIdx.x * ROWS;

    if (t < NN) {
        float dv = DEV_MIN_F + (float)t * DEV_STEP_F;
        sprm[t] = make_float2(-0.5f / (dv * dv), -2.f * __logf(dv) - LOG2PI_F);
    }
    // load 4 rows of latents (4 KB) with one float4 per thread
    ((float4*)&hbuf[0][0][0])[t] = ((const float4*)(latents + brow * 256))[t];
    __syncthreads();

    const float* Ws[6] = {W0, W1, W2, W3, W4, Wt};
    const float* bs[6] = {b0, b1, b2, b3, b4, bp};

    int cur = 0;
    #pragma unroll 1
    for (int layer = 0; layer < 6; ++layer) {
        const float* __restrict__ W = Ws[layer];
        const bool last = (layer == 5);
        float a0 = 0.f, a1 = 0.f, a2 = 0.f, a3 = 0.f;
        #pragma unroll 4
        for (int k = 0; k < 256; k += 4) {
            float w0 = W[(k + 0) * 256 + t];
            float w1 = W[(k + 1) * 256 + t];
            float w2 = W[(k + 2) * 256 + t];
            float w3 = W[(k + 3) * 256 + t];
            float4 h0 = *(const float4*)&hbuf[cur][0][k];
            float4 h1 = *(const float4*)&hbuf[cur][1][k];
            float4 h2 = *(const float4*)&hbuf[cur][2][k];
            float4 h3 = *(const float4*)&hbuf[cur][3][k];
            a0 = fmaf(h0.x, w0, a0); a0 = fmaf(h0.y, w1, a0);
            a0 = fmaf(h0.z, w2, a0); a0 = fmaf(h0.w, w3, a0);
            a1 = fmaf(h1.x, w0, a1); a1 = fmaf(h1.y, w1, a1);
            a1 = fmaf(h1.z, w2, a1); a1 = fmaf(h1.w, w3, a1);
            a2 = fmaf(h2.x, w0, a2); a2 = fmaf(h2.y, w1, a2);
            a2 = fmaf(h2.z, w2, a2); a2 = fmaf(h2.w, w3, a2);
            a3 = fmaf(h3.x, w0, a3); a3 = fmaf(h3.y, w1, a3);
            a3 = fmaf(h3.z, w2, a3); a3 = fmaf(h3.w, w3, a3);
        }
        float bias = bs[layer][t] + (last ? 0.5f : 0.f);
        a0 += bias; a1 += bias; a2 += bias; a3 += bias;
        if (!last) {
            a0 = fmaxf(a0, 0.f); a1 = fmaxf(a1, 0.f);
            a2 = fmaxf(a2, 0.f); a3 = fmaxf(a3, 0.f);
        }
        hbuf[cur ^ 1][0][t] = a0;
        hbuf[cur ^ 1][1][t] = a1;
        hbuf[cur ^ 1][2][t] = a2;
        hbuf[cur ^ 1][3][t] = a3;
        __syncthreads();
        cur ^= 1;
    }

    // ---- loss phase: mu for rows brow..brow+3 sits in hbuf[cur] ----
    const float* __restrict__ muL = &hbuf[cur][0][0];  // muL[r*256 + 2m + c]
    const int n = t >> 1;
    const int s = t & 1;
    const float devn = DEV_MIN_F + (float)n * DEV_STEP_F;
    const float2 prn = sprm[n];

    float px[ROWS], py[ROWS];
    #pragma unroll
    for (int r = 0; r < ROWS; ++r) {
        float2 ep = ((const float2*)eps)[s * (BB * NN) + (brow + r) * NN + n];
        px[r] = fmaf(devn, ep.x, muL[r * 256 + 2 * n]);
        py[r] = fmaf(devn, ep.y, muL[r * 256 + 2 * n + 1]);
    }

    // sampled: (s*N+n, brow..brow+3, :) = 32 contiguous bytes
    {
        float4 v0 = make_float4(px[0], py[0], px[1], py[1]);
        float4 v1 = make_float4(px[2], py[2], px[3], py[3]);
        float4* dst = (float4*)(out + (size_t)(s * NN + n) * 2048 + brow * 2);
        dst[0] = v0;
        dst[1] = v1;
    }

    // ---- lossB: two-pass softmax over 128 modes, 4 rows jointly for ILP ----
    float mx[ROWS] = {-1e30f, -1e30f, -1e30f, -1e30f};
    #pragma unroll 2
    for (int m = 0; m < NN; ++m) {
        float2 pr = sprm[m];
        #pragma unroll
        for (int r = 0; r < ROWS; ++r) {
            float2 mm = *(const float2*)&muL[r * 256 + 2 * m];
            float dx = px[r] - mm.x, dy = py[r] - mm.y;
            float lb = fmaf(fmaf(dx, dx, dy * dy), pr.x, pr.y);
            mx[r] = fmaxf(mx[r], lb);
        }
    }
    float sum[ROWS] = {0.f, 0.f, 0.f, 0.f};
    float edg[ROWS] = {0.f, 0.f, 0.f, 0.f};
    #pragma unroll 2
    for (int m = 0; m < NN; ++m) {
        float2 pr = sprm[m];
        #pragma unroll
        for (int r = 0; r < ROWS; ++r) {
            float2 mm = *(const float2*)&muL[r * 256 + 2 * m];
            float dx = px[r] - mm.x, dy = py[r] - mm.y;
            float lb = fmaf(fmaf(dx, dx, dy * dy), pr.x, pr.y);
            float e = __expf(lb - mx[r]);
            sum[r] += e;
            if (m == n) edg[r] = e;
        }
    }
    #pragma unroll
    for (int r = 0; r < ROWS; ++r) {
        float d = edg[r] / sum[r];
        float v = (1.f - d) * (1.f - d);
        out[OFF_B + (size_t)(brow + r) * (NN * SS) + t] = v;
    }

    // ---- per-row scalar losses ----
    #pragma unroll
    for (int r = 0; r < ROWS; ++r) {
        const int b = brow + r;
        const float pmx = predMu[b * 2],    pmy = predMu[b * 2 + 1];
        const float psx = predScale[b * 2], psy = predScale[b * 2 + 1];
        float zx = (px[r] - pmx) / psx, zy = (py[r] - pmy) / psy;
        float la = -0.5f * (zx * zx + zy * zy) - __logf(psx) - __logf(psy) - LOG2PI_F;
        float aa = 1.f / (1.f + __expf(la));    // sigmoid(-la)
        float termA = LOG1P_HALF - log1pf(aa);
        termA = termA * termA;
        float gg = 1.f / (1.f + __expf(-la));   // sigmoid(la)

        // realLoss (depends on (b, n) only)
        const float rx = realPts[b * 2], ry = realPts[b * 2 + 1];
        float mux = muL[r * 256 + 2 * n], muy = muL[r * 256 + 2 * n + 1];
        float drx = rx - mux, dry = ry - muy;
        float lr = fmaf(fmaf(drx, drx, dry * dry), prn.x, prn.y);
        float rl = 1.f / (1.f + __expf(-lr));

        float termA_sum = termA + __shfl_xor(termA, 1);
        float gg_sum    = gg + __shfl_xor(gg, 1);
        if (s == 0) {
            out[OFF_GEN  + (size_t)b * NN + n] = 0.5f * gg_sum * (1.f - rl);
            out[OFF_REAL + (size_t)b * NN + n] = rl;
            out[OFF_A    + (size_t)b * NN + n] = 0.5f * termA_sum;
        }
    }
}

// ---------------------------------------------------------------------------
extern "C" void kernel_launch(void* const* d_in, const int* in_sizes, int n_in,
                              void* d_out, int out_size, void* d_ws, size_t ws_size,
                              hipStream_t stream) {
    const float* latents   = (const float*)d_in[0];
    const float* realPts   = (const float*)d_in[1];
    const float* predMu    = (const float*)d_in[2];
    const float* predScale = (const float*)d_in[3];
    const float* eps       = (const float*)d_in[4];
    const float* W0 = (const float*)d_in[5];
    const float* b0 = (const float*)d_in[6];
    const float* W1 = (const float*)d_in[7];
    const float* b1 = (const float*)d_in[8];
    const float* W2 = (const float*)d_in[9];
    const float* b2 = (const float*)d_in[10];
    const float* W3 = (const float*)d_in[11];
    const float* b3 = (const float*)d_in[12];
    const float* W4 = (const float*)d_in[13];
    const float* b4 = (const float*)d_in[14];
    const float* Wp = (const float*)d_in[15];
    const float* bp = (const float*)d_in[16];

    float* Wt = (float*)d_ws;  // 256 KB

    transpose_wp_kernel<<<dim3(256), dim3(256), 0, stream>>>(Wp, Wt);
    fused_kernel<<<dim3(BB / ROWS), dim3(256), 0, stream>>>(
        latents, eps, realPts, predMu, predScale,
        W0, b0, W1, b1, W2, b2, W3, b3, W4, b4, Wt, bp, (float*)d_out);
}

// Round 3
// 158.550 us; speedup vs baseline: 1.1164x; 1.1097x over previous
//
#include <hip/hip_runtime.h>
#include <math.h>

#define BB   1024
#define HH   256
#define NN   128
#define SS   2
#define LOG2PI_F 1.8378770664093453f
#define DEV_MIN_F 0.001f
#define DEV_STEP_F 7.08661417322835e-05f   // (0.01-0.001)/127
#define LOG1P_HALF 0.40546510810816438f    // log1p(0.5)
#define SHIFT_F 12.0f                       // > max lb = -2ln(0.001)-log2pi = 11.98

// Output layout (flat concat, fp32):
//   sampled  (S*N, B, 2) @ 0
//   genLoss  (B, N)      @ 524288
//   realLoss (B, N)      @ 655360
//   lossA    (B, N)      @ 786432
//   lossB    (B, N, S)   @ 917504
#define OFF_GEN  524288
#define OFF_REAL 655360
#define OFF_A    786432
#define OFF_B    917504

// ---------------------------------------------------------------------------
// Pre-transpose Wp (N,H,2) -> Wt[k][j] = Wp[j>>1][k][j&1]  (256x256 row-major)
// ---------------------------------------------------------------------------
__global__ __launch_bounds__(256) void transpose_wp_kernel(
    const float* __restrict__ Wp, float* __restrict__ Wt) {
    const int k = blockIdx.x;
    const int j = threadIdx.x;
    Wt[k * 256 + j] = Wp[(j >> 1) * 512 + k * 2 + (j & 1)];
}

// ---------------------------------------------------------------------------
// Fully fused MLP + losses.
// Grid 512 blocks x 512 threads (2 blocks/CU, 16 waves/CU = 4/SIMD).
// Block owns 2 batch rows. MLP phase: thread = (rh = t>>8, j = t&255),
// 1 accumulator (row brow+rh, col j). W loads coalesced per wave; duplicate
// streams across rh-halves/blocks dedup in L1/L2. h reads are LDS broadcasts.
// Deep register prefetch (8-deep ping-pong) keeps 8 W loads in flight.
// Loss phase: thread = (rh, n = j>>1, s = j&1), one sample point each;
// one-pass softmax with fixed shift (no max pass).
// ---------------------------------------------------------------------------
__global__ __launch_bounds__(512, 4) void mlp_loss_kernel(
    const float* __restrict__ latents,   // (B, 256)
    const float* __restrict__ eps,       // (S, B*N, 2)
    const float* __restrict__ realPts,   // (B, 2)
    const float* __restrict__ predMu,    // (B, 2)
    const float* __restrict__ predScale, // (B, 2)
    const float* __restrict__ W0, const float* __restrict__ b0,
    const float* __restrict__ W1, const float* __restrict__ b1,
    const float* __restrict__ W2, const float* __restrict__ b2,
    const float* __restrict__ W3, const float* __restrict__ b3,
    const float* __restrict__ W4, const float* __restrict__ b4,
    const float* __restrict__ Wt,        // (256,256) pre-transposed Wp
    const float* __restrict__ bp,        // (N,2) flat == bias[j]
    float* __restrict__ out) {
    __shared__ float  hbuf[2][2][256];   // [buf][row][col], 4 KB
    __shared__ float2 sprm[NN];          // (-0.5/dev^2, -2*log(dev)-LOG2PI)

    const int t    = threadIdx.x;
    const int rh   = t >> 8;             // 0/1: which of the 2 rows
    const int j    = t & 255;            // column
    const int brow = blockIdx.x * 2;

    if (t < NN) {
        float dv = DEV_MIN_F + (float)t * DEV_STEP_F;
        sprm[t] = make_float2(-0.5f / (dv * dv), -2.f * __logf(dv) - LOG2PI_F);
    }
    hbuf[0][rh][j] = latents[brow * 256 + t];   // 2 rows, coalesced
    __syncthreads();

    const float* Ws[6] = {W0, W1, W2, W3, W4, Wt};
    const float* bs[6] = {b0, b1, b2, b3, b4, bp};

    int cur = 0;
    #pragma unroll 1
    for (int layer = 0; layer < 6; ++layer) {
        const float* __restrict__ Wl = Ws[layer] + j;   // column j, stride 256
        const float* __restrict__ hrow = &hbuf[cur][rh][0];
        float acc = 0.f;
        float wa[8], wb[8];
        #pragma unroll
        for (int p = 0; p < 8; ++p) wa[p] = Wl[p * 256];

        #pragma unroll 1
        for (int k0 = 0; k0 < 256; k0 += 16) {
            // prefetch next 8 while consuming wa
            #pragma unroll
            for (int p = 0; p < 8; ++p) wb[p] = Wl[(((k0 + 8 + p) & 255)) * 256];
            float4 h0 = *(const float4*)&hrow[k0];
            float4 h1 = *(const float4*)&hrow[k0 + 4];
            acc = fmaf(h0.x, wa[0], acc); acc = fmaf(h0.y, wa[1], acc);
            acc = fmaf(h0.z, wa[2], acc); acc = fmaf(h0.w, wa[3], acc);
            acc = fmaf(h1.x, wa[4], acc); acc = fmaf(h1.y, wa[5], acc);
            acc = fmaf(h1.z, wa[6], acc); acc = fmaf(h1.w, wa[7], acc);
            // prefetch chunk after next while consuming wb
            #pragma unroll
            for (int p = 0; p < 8; ++p) wa[p] = Wl[(((k0 + 16 + p) & 255)) * 256];
            float4 h2 = *(const float4*)&hrow[k0 + 8];
            float4 h3 = *(const float4*)&hrow[k0 + 12];
            acc = fmaf(h2.x, wb[0], acc); acc = fmaf(h2.y, wb[1], acc);
            acc = fmaf(h2.z, wb[2], acc); acc = fmaf(h2.w, wb[3], acc);
            acc = fmaf(h3.x, wb[4], acc); acc = fmaf(h3.y, wb[5], acc);
            acc = fmaf(h3.z, wb[6], acc); acc = fmaf(h3.w, wb[7], acc);
        }

        acc += bs[layer][j];
        if (layer == 5) acc += 0.5f;
        else            acc = fmaxf(acc, 0.f);
        hbuf[cur ^ 1][rh][j] = acc;
        __syncthreads();
        cur ^= 1;
    }

    // ---- loss phase: mu for row (brow+rh) sits in hbuf[cur][rh] ----
    const float* __restrict__ muL = &hbuf[cur][rh][0];  // muL[2m + c]
    const int b = brow + rh;
    const int n = j >> 1;
    const int s = j & 1;
    const float devn = DEV_MIN_F + (float)n * DEV_STEP_F;
    const float2 prn = sprm[n];

    const float2 ep = ((const float2*)eps)[s * (BB * NN) + b * NN + n];
    const float mux = muL[2 * n], muy = muL[2 * n + 1];
    const float px = fmaf(devn, ep.x, mux);
    const float py = fmaf(devn, ep.y, muy);

    // sampled
    ((float2*)out)[(size_t)(s * NN + n) * BB + b] = make_float2(px, py);

    // lossB: one-pass shifted softmax over 128 modes, m unrolled by 2
    float sum0 = 0.f, sum1 = 0.f;
    #pragma unroll 4
    for (int m = 0; m < NN; m += 2) {
        float4 mm = *(const float4*)&muL[2 * m];    // mu[m], mu[m+1]
        float4 pr = *(const float4*)&sprm[m];       // sprm[m], sprm[m+1]
        float dx0 = px - mm.x, dy0 = py - mm.y;
        float lb0 = fmaf(fmaf(dx0, dx0, dy0 * dy0), pr.x, pr.y);
        sum0 += __expf(lb0 - SHIFT_F);
        float dx1 = px - mm.z, dy1 = py - mm.w;
        float lb1 = fmaf(fmaf(dx1, dx1, dy1 * dy1), pr.z, pr.w);
        sum1 += __expf(lb1 - SHIFT_F);
    }
    // diagonal term closed-form: dx = devn*ep.x -> lb = -0.5|eps|^2 + prn.y
    float dxd = devn * ep.x, dyd = devn * ep.y;
    float lbd = fmaf(fmaf(dxd, dxd, dyd * dyd), prn.x, prn.y);
    float ed  = __expf(lbd - SHIFT_F);
    float diag = ed / (sum0 + sum1);
    float lbv = (1.f - diag) * (1.f - diag);
    out[OFF_B + (size_t)b * (NN * SS) + j] = lbv;   // (B,N,S), j == n*2+s

    // lossA / genLoss (per point, under predicted dist)
    const float pmx = predMu[b * 2],    pmy = predMu[b * 2 + 1];
    const float psx = predScale[b * 2], psy = predScale[b * 2 + 1];
    float zx = (px - pmx) / psx, zy = (py - pmy) / psy;
    float la = -0.5f * (zx * zx + zy * zy) - __logf(psx) - __logf(psy) - LOG2PI_F;
    float aa = 1.f / (1.f + __expf(la));    // sigmoid(-la)
    float termA = LOG1P_HALF - log1pf(aa);
    termA = termA * termA;
    float gg = 1.f / (1.f + __expf(-la));   // sigmoid(la)

    // realLoss (depends on (b,n) only)
    const float rx = realPts[b * 2], ry = realPts[b * 2 + 1];
    float drx = rx - mux, dry = ry - muy;
    float lr = fmaf(fmaf(drx, drx, dry * dry), prn.x, prn.y);
    float rl = 1.f / (1.f + __expf(-lr));

    // reduce over s (adjacent lanes: lane bit 0 == s)
    float termA_sum = termA + __shfl_xor(termA, 1);
    float gg_sum    = gg + __shfl_xor(gg, 1);
    if (s == 0) {
        out[OFF_GEN  + (size_t)b * NN + n] = 0.5f * gg_sum * (1.f - rl);
        out[OFF_REAL + (size_t)b * NN + n] = rl;
        out[OFF_A    + (size_t)b * NN + n] = 0.5f * termA_sum;
    }
}

// ---------------------------------------------------------------------------
extern "C" void kernel_launch(void* const* d_in, const int* in_sizes, int n_in,
                              void* d_out, int out_size, void* d_ws, size_t ws_size,
                              hipStream_t stream) {
    const float* latents   = (const float*)d_in[0];
    const float* realPts   = (const float*)d_in[1];
    const float* predMu    = (const float*)d_in[2];
    const float* predScale = (const float*)d_in[3];
    const float* eps       = (const float*)d_in[4];
    const float* W0 = (const float*)d_in[5];
    const float* b0 = (const float*)d_in[6];
    const float* W1 = (const float*)d_in[7];
    const float* b1 = (const float*)d_in[8];
    const float* W2 = (const float*)d_in[9];
    const float* b2 = (const float*)d_in[10];
    const float* W3 = (const float*)d_in[11];
    const float* b3 = (const float*)d_in[12];
    const float* W4 = (const float*)d_in[13];
    const float* b4 = (const float*)d_in[14];
    const float* Wp = (const float*)d_in[15];
    const float* bp = (const float*)d_in[16];

    float* Wt = (float*)d_ws;  // 256 KB

    transpose_wp_kernel<<<dim3(256), dim3(256), 0, stream>>>(Wp, Wt);
    mlp_loss_kernel<<<dim3(BB / 2), dim3(512), 0, stream>>>(
        latents, eps, realPts, predMu, predScale,
        W0, b0, W1, b1, W2, b2, W3, b3, W4, b4, Wt, bp, (float*)d_out);
}

// Round 4
// 135.038 us; speedup vs baseline: 1.3108x; 1.1741x over previous
//
#include <hip/hip_runtime.h>
#include <math.h>

#define BB   1024
#define HH   256
#define NN   128
#define SS   2
#define RR   4                              // rows per block == K-quarters
#define LOG2PI_F 1.8378770664093453f
#define DEV_MIN_F 0.001f
#define DEV_STEP_F 7.08661417322835e-05f   // (0.01-0.001)/127
#define LOG1P_HALF 0.40546510810816438f    // log1p(0.5)
#define SHIFT_F 12.0f                       // > max lb = -2ln(0.001)-log2pi = 11.98

// Output layout (flat concat, fp32):
//   sampled  (S*N, B, 2) @ 0
//   genLoss  (B, N)      @ 524288
//   realLoss (B, N)      @ 655360
//   lossA    (B, N)      @ 786432
//   lossB    (B, N, S)   @ 917504
#define OFF_GEN  524288
#define OFF_REAL 655360
#define OFF_A    786432
#define OFF_B    917504

// ---------------------------------------------------------------------------
// Pre-transpose Wp (N,H,2) -> Wt[k][j] = Wp[j>>1][k][j&1]  (256x256 row-major)
// ---------------------------------------------------------------------------
__global__ __launch_bounds__(256) void transpose_wp_kernel(
    const float* __restrict__ Wp, float* __restrict__ Wt) {
    const int k = blockIdx.x;
    const int j = threadIdx.x;
    Wt[k * 256 + j] = Wp[(j >> 1) * 512 + k * 2 + (j & 1)];
}

// ---------------------------------------------------------------------------
// Fully fused MLP + losses. Grid 256 blocks x 1024 threads (1 block/CU,
// 16 waves/CU = 4/SIMD). Block owns RR=4 batch rows.
// MLP phase: thread = (q = t>>8 K-quarter, j = t&255 column). Each thread
// accumulates 4 rows over its 64-k quarter -> W is read EXACTLY ONCE per
// block per layer (256 KB/CU/layer, the fused-MLP L2 floor). Partials are
// combined via LDS; thread (q,j) finalizes row r=q.
// W loads coalesced + 8-deep ping-pong register prefetch. h reads are LDS
// broadcasts (wave-uniform address).
// Loss phase: 1 point per thread (r = t>>8, n = (t&255)>>1, s = t&1);
// one-pass shifted softmax (max lb bounded by 12).
// ---------------------------------------------------------------------------
__global__ __launch_bounds__(1024, 4) void mlp_loss_kernel(
    const float* __restrict__ latents,   // (B, 256)
    const float* __restrict__ eps,       // (S, B*N, 2)
    const float* __restrict__ realPts,   // (B, 2)
    const float* __restrict__ predMu,    // (B, 2)
    const float* __restrict__ predScale, // (B, 2)
    const float* __restrict__ W0, const float* __restrict__ b0,
    const float* __restrict__ W1, const float* __restrict__ b1,
    const float* __restrict__ W2, const float* __restrict__ b2,
    const float* __restrict__ W3, const float* __restrict__ b3,
    const float* __restrict__ W4, const float* __restrict__ b4,
    const float* __restrict__ Wt,        // (256,256) pre-transposed Wp
    const float* __restrict__ bp,        // (N,2) flat == bias[j]
    float* __restrict__ out) {
    __shared__ float  hbuf[2][RR][256];      // 8 KB, double-buffered activations
    __shared__ float  part[RR][RR][256];     // 16 KB, [q][row][col] partials
    __shared__ float2 sprm[NN];              // (-0.5/dev^2, -2*log(dev)-LOG2PI)

    const int t    = threadIdx.x;
    const int q    = t >> 8;                 // K-quarter (== finalized row)
    const int j    = t & 255;                // column
    const int brow = blockIdx.x * RR;

    if (t < NN) {
        float dv = DEV_MIN_F + (float)t * DEV_STEP_F;
        sprm[t] = make_float2(-0.5f / (dv * dv), -2.f * __logf(dv) - LOG2PI_F);
    }
    hbuf[0][q][j] = latents[(brow + q) * 256 + j];   // coalesced, 4 rows

    // prefetch this thread's eps for the loss phase (held in 2 VGPRs)
    const int nL = j >> 1;
    const int sL = j & 1;
    const float2 epv = ((const float2*)eps)[sL * (BB * NN) + (brow + q) * NN + nL];

    __syncthreads();

    const float* Ws[6] = {W0, W1, W2, W3, W4, Wt};
    const float* bs[6] = {b0, b1, b2, b3, b4, bp};

    int cur = 0;
    #pragma unroll 1
    for (int layer = 0; layer < 6; ++layer) {
        // this thread streams W[(q*64 + kk)*256 + j], kk in [0,64)
        const float* __restrict__ Wl = Ws[layer] + (size_t)(q * 64) * 256 + j;
        const float* __restrict__ h0p = &hbuf[cur][0][q * 64];
        const float* __restrict__ h1p = &hbuf[cur][1][q * 64];
        const float* __restrict__ h2p = &hbuf[cur][2][q * 64];
        const float* __restrict__ h3p = &hbuf[cur][3][q * 64];
        float a0 = 0.f, a1 = 0.f, a2 = 0.f, a3 = 0.f;
        float wa[8], wb[8];
        #pragma unroll
        for (int p = 0; p < 8; ++p) wa[p] = Wl[p * 256];

        #pragma unroll 1
        for (int kk = 0; kk < 64; kk += 16) {
            #pragma unroll
            for (int p = 0; p < 8; ++p) wb[p] = Wl[((kk + 8 + p) & 63) * 256];
            {
                float4 ha0 = *(const float4*)&h0p[kk], hb0 = *(const float4*)&h0p[kk + 4];
                float4 ha1 = *(const float4*)&h1p[kk], hb1 = *(const float4*)&h1p[kk + 4];
                float4 ha2 = *(const float4*)&h2p[kk], hb2 = *(const float4*)&h2p[kk + 4];
                float4 ha3 = *(const float4*)&h3p[kk], hb3 = *(const float4*)&h3p[kk + 4];
                a0 = fmaf(ha0.x, wa[0], a0); a0 = fmaf(ha0.y, wa[1], a0);
                a0 = fmaf(ha0.z, wa[2], a0); a0 = fmaf(ha0.w, wa[3], a0);
                a0 = fmaf(hb0.x, wa[4], a0); a0 = fmaf(hb0.y, wa[5], a0);
                a0 = fmaf(hb0.z, wa[6], a0); a0 = fmaf(hb0.w, wa[7], a0);
                a1 = fmaf(ha1.x, wa[0], a1); a1 = fmaf(ha1.y, wa[1], a1);
                a1 = fmaf(ha1.z, wa[2], a1); a1 = fmaf(ha1.w, wa[3], a1);
                a1 = fmaf(hb1.x, wa[4], a1); a1 = fmaf(hb1.y, wa[5], a1);
                a1 = fmaf(hb1.z, wa[6], a1); a1 = fmaf(hb1.w, wa[7], a1);
                a2 = fmaf(ha2.x, wa[0], a2); a2 = fmaf(ha2.y, wa[1], a2);
                a2 = fmaf(ha2.z, wa[2], a2); a2 = fmaf(ha2.w, wa[3], a2);
                a2 = fmaf(hb2.x, wa[4], a2); a2 = fmaf(hb2.y, wa[5], a2);
                a2 = fmaf(hb2.z, wa[6], a2); a2 = fmaf(hb2.w, wa[7], a2);
                a3 = fmaf(ha3.x, wa[0], a3); a3 = fmaf(ha3.y, wa[1], a3);
                a3 = fmaf(ha3.z, wa[2], a3); a3 = fmaf(ha3.w, wa[3], a3);
                a3 = fmaf(hb3.x, wa[4], a3); a3 = fmaf(hb3.y, wa[5], a3);
                a3 = fmaf(hb3.z, wa[6], a3); a3 = fmaf(hb3.w, wa[7], a3);
            }
            #pragma unroll
            for (int p = 0; p < 8; ++p) wa[p] = Wl[((kk + 16 + p) & 63) * 256];
            {
                int k2 = kk + 8;
                float4 ha0 = *(const float4*)&h0p[k2], hb0 = *(const float4*)&h0p[k2 + 4];
                float4 ha1 = *(const float4*)&h1p[k2], hb1 = *(const float4*)&h1p[k2 + 4];
                float4 ha2 = *(const float4*)&h2p[k2], hb2 = *(const float4*)&h2p[k2 + 4];
                float4 ha3 = *(const float4*)&h3p[k2], hb3 = *(const float4*)&h3p[k2 + 4];
                a0 = fmaf(ha0.x, wb[0], a0); a0 = fmaf(ha0.y, wb[1], a0);
                a0 = fmaf(ha0.z, wb[2], a0); a0 = fmaf(ha0.w, wb[3], a0);
                a0 = fmaf(hb0.x, wb[4], a0); a0 = fmaf(hb0.y, wb[5], a0);
                a0 = fmaf(hb0.z, wb[6], a0); a0 = fmaf(hb0.w, wb[7], a0);
                a1 = fmaf(ha1.x, wb[0], a1); a1 = fmaf(ha1.y, wb[1], a1);
                a1 = fmaf(ha1.z, wb[2], a1); a1 = fmaf(ha1.w, wb[3], a1);
                a1 = fmaf(hb1.x, wb[4], a1); a1 = fmaf(hb1.y, wb[5], a1);
                a1 = fmaf(hb1.z, wb[6], a1); a1 = fmaf(hb1.w, wb[7], a1);
                a2 = fmaf(ha2.x, wb[0], a2); a2 = fmaf(ha2.y, wb[1], a2);
                a2 = fmaf(ha2.z, wb[2], a2); a2 = fmaf(ha2.w, wb[3], a2);
                a2 = fmaf(hb2.x, wb[4], a2); a2 = fmaf(hb2.y, wb[5], a2);
                a2 = fmaf(hb2.z, wb[6], a2); a2 = fmaf(hb2.w, wb[7], a2);
                a3 = fmaf(ha3.x, wb[0], a3); a3 = fmaf(ha3.y, wb[1], a3);
                a3 = fmaf(ha3.z, wb[2], a3); a3 = fmaf(ha3.w, wb[3], a3);
                a3 = fmaf(hb3.x, wb[4], a3); a3 = fmaf(hb3.y, wb[5], a3);
                a3 = fmaf(hb3.z, wb[6], a3); a3 = fmaf(hb3.w, wb[7], a3);
            }
        }

        part[q][0][j] = a0;
        part[q][1][j] = a1;
        part[q][2][j] = a2;
        part[q][3][j] = a3;
        __syncthreads();

        // thread (q, j) finalizes row r = q
        float val = part[0][q][j] + part[1][q][j] + part[2][q][j] + part[3][q][j];
        val += bs[layer][j];
        if (layer == 5) val += 0.5f;
        else            val = fmaxf(val, 0.f);
        hbuf[cur ^ 1][q][j] = val;
        __syncthreads();
        cur ^= 1;
    }

    // ---- loss phase: mu for row (brow+q) sits in hbuf[cur][q] ----
    const float* __restrict__ muL = &hbuf[cur][q][0];  // muL[2m + c], wave-uniform row
    const int b = brow + q;
    const int n = nL, s = sL;
    const float devn = DEV_MIN_F + (float)n * DEV_STEP_F;
    const float2 prn = sprm[n];

    const float mux = muL[2 * n], muy = muL[2 * n + 1];
    const float px = fmaf(devn, epv.x, mux);
    const float py = fmaf(devn, epv.y, muy);

    // sampled
    ((float2*)out)[(size_t)(s * NN + n) * BB + b] = make_float2(px, py);

    // lossB: one-pass shifted softmax over 128 modes
    float sum0 = 0.f, sum1 = 0.f;
    #pragma unroll 4
    for (int m = 0; m < NN; m += 2) {
        float4 mm = *(const float4*)&muL[2 * m];    // mu[m], mu[m+1]  (broadcast)
        float4 pr = *(const float4*)&sprm[m];       // sprm[m], sprm[m+1]
        float dx0 = px - mm.x, dy0 = py - mm.y;
        float lb0 = fmaf(fmaf(dx0, dx0, dy0 * dy0), pr.x, pr.y);
        sum0 += __expf(lb0 - SHIFT_F);
        float dx1 = px - mm.z, dy1 = py - mm.w;
        float lb1 = fmaf(fmaf(dx1, dx1, dy1 * dy1), pr.z, pr.w);
        sum1 += __expf(lb1 - SHIFT_F);
    }
    // diagonal closed-form: dx = devn*eps -> lb = prn.x*devn^2*|eps|^2 + prn.y
    float dxd = devn * epv.x, dyd = devn * epv.y;
    float lbd = fmaf(fmaf(dxd, dxd, dyd * dyd), prn.x, prn.y);
    float ed  = __expf(lbd - SHIFT_F);
    float diag = ed / (sum0 + sum1);
    float lbv = (1.f - diag) * (1.f - diag);
    out[OFF_B + (size_t)b * (NN * SS) + j] = lbv;   // (B,N,S), j == n*2+s

    // lossA / genLoss under predicted dist
    const float pmx = predMu[b * 2],    pmy = predMu[b * 2 + 1];
    const float psx = predScale[b * 2], psy = predScale[b * 2 + 1];
    float zx = (px - pmx) / psx, zy = (py - pmy) / psy;
    float la = -0.5f * (zx * zx + zy * zy) - __logf(psx) - __logf(psy) - LOG2PI_F;
    float aa = 1.f / (1.f + __expf(la));    // sigmoid(-la)
    float termA = LOG1P_HALF - log1pf(aa);
    termA = termA * termA;
    float gg = 1.f / (1.f + __expf(-la));   // sigmoid(la)

    // realLoss (depends on (b,n) only)
    const float rx = realPts[b * 2], ry = realPts[b * 2 + 1];
    float drx = rx - mux, dry = ry - muy;
    float lr = fmaf(fmaf(drx, drx, dry * dry), prn.x, prn.y);
    float rl = 1.f / (1.f + __expf(-lr));

    // reduce over s (adjacent lanes: lane bit 0 == s)
    float termA_sum = termA + __shfl_xor(termA, 1);
    float gg_sum    = gg + __shfl_xor(gg, 1);
    if (s == 0) {
        out[OFF_GEN  + (size_t)b * NN + n] = 0.5f * gg_sum * (1.f - rl);
        out[OFF_REAL + (size_t)b * NN + n] = rl;
        out[OFF_A    + (size_t)b * NN + n] = 0.5f * termA_sum;
    }
}

// ---------------------------------------------------------------------------
extern "C" void kernel_launch(void* const* d_in, const int* in_sizes, int n_in,
                              void* d_out, int out_size, void* d_ws, size_t ws_size,
                              hipStream_t stream) {
    const float* latents   = (const float*)d_in[0];
    const float* realPts   = (const float*)d_in[1];
    const float* predMu    = (const float*)d_in[2];
    const float* predScale = (const float*)d_in[3];
    const float* eps       = (const float*)d_in[4];
    const float* W0 = (const float*)d_in[5];
    const float* b0 = (const float*)d_in[6];
    const float* W1 = (const float*)d_in[7];
    const float* b1 = (const float*)d_in[8];
    const float* W2 = (const float*)d_in[9];
    const float* b2 = (const float*)d_in[10];
    const float* W3 = (const float*)d_in[11];
    const float* b3 = (const float*)d_in[12];
    const float* W4 = (const float*)d_in[13];
    const float* b4 = (const float*)d_in[14];
    const float* Wp = (const float*)d_in[15];
    const float* bp = (const float*)d_in[16];

    float* Wt = (float*)d_ws;  // 256 KB

    transpose_wp_kernel<<<dim3(256), dim3(256), 0, stream>>>(Wp, Wt);
    mlp_loss_kernel<<<dim3(BB / RR), dim3(1024), 0, stream>>>(
        latents, eps, realPts, predMu, predScale,
        W0, b0, W1, b1, W2, b2, W3, b3, W4, b4, Wt, bp, (float*)d_out);
}

// Round 5
// 125.901 us; speedup vs baseline: 1.4059x; 1.0726x over previous
//
#include <hip/hip_runtime.h>
#include <math.h>

#define BB   1024
#define HH   256
#define NN   128
#define SS   2
#define RR   4                              // batch rows per block
#define LOG2PI_F 1.8378770664093453f
#define DEV_MIN_F 0.001f
#define DEV_STEP_F 7.08661417322835e-05f   // (0.01-0.001)/127
#define LOG1P_HALF 0.40546510810816438f    // log1p(0.5)
#define SHIFT_F 12.0f                       // > max lb = -2ln(0.001)-log2pi = 11.98

// Output layout (flat concat, fp32):
#define OFF_GEN  524288
#define OFF_REAL 655360
#define OFF_A    786432
#define OFF_B    917504

// ---------------------------------------------------------------------------
// Pre-transpose Wp (N,H,2) -> Wt[k][j] = Wp[j>>1][k][j&1]  (256x256 row-major)
// ---------------------------------------------------------------------------
__global__ __launch_bounds__(256) void transpose_wp_kernel(
    const float* __restrict__ Wp, float* __restrict__ Wt) {
    const int k = blockIdx.x;
    const int j = threadIdx.x;
    Wt[k * 256 + j] = Wp[(j >> 1) * 512 + k * 2 + (j & 1)];
}

__device__ __forceinline__ void step8(float h0k, float h1k, float h2k, float h3k,
                                      float2 wv, float2& a0, float2& a1,
                                      float2& a2, float2& a3) {
    a0.x = fmaf(h0k, wv.x, a0.x); a0.y = fmaf(h0k, wv.y, a0.y);
    a1.x = fmaf(h1k, wv.x, a1.x); a1.y = fmaf(h1k, wv.y, a1.y);
    a2.x = fmaf(h2k, wv.x, a2.x); a2.y = fmaf(h2k, wv.y, a2.y);
    a3.x = fmaf(h3k, wv.x, a3.x); a3.y = fmaf(h3k, wv.y, a3.y);
}

// Consume one 16-k bank (HOFF = 0 or 16 within this thread's 32-k slice)
#define CONSUME(BANK, HOFF)                                                    \
    {                                                                          \
        _Pragma("unroll")                                                      \
        for (int k4 = 0; k4 < 16; k4 += 4) {                                   \
            float4 h0 = *(const float4*)&h0p[(HOFF) + k4];                     \
            float4 h1 = *(const float4*)&h1p[(HOFF) + k4];                     \
            float4 h2 = *(const float4*)&h2p[(HOFF) + k4];                     \
            float4 h3 = *(const float4*)&h3p[(HOFF) + k4];                     \
            step8(h0.x, h1.x, h2.x, h3.x, BANK[k4 + 0], acc0, acc1, acc2, acc3); \
            step8(h0.y, h1.y, h2.y, h3.y, BANK[k4 + 1], acc0, acc1, acc2, acc3); \
            step8(h0.z, h1.z, h2.z, h3.z, BANK[k4 + 2], acc0, acc1, acc2, acc3); \
            step8(h0.w, h1.w, h2.w, h3.w, BANK[k4 + 3], acc0, acc1, acc2, acc3); \
        }                                                                      \
    }

// ---------------------------------------------------------------------------
// Fully fused MLP + losses. Grid 256 x 1024 (1 block/CU, 16 waves).
// MLP: thread = (q = t>>7 K-eighth, c = t&127 col-pair). dwordx2 W loads,
// coalesced; W read EXACTLY once per CU per layer. 16-deep double-banked
// register prefetch, pipelined ACROSS layers (bank A of layer L+1 issues
// before layer L's barriers -> loads in flight through the barrier drain).
// Partials (8-way K-split) combine via 32 KB LDS; thread (t>>8, t&255)
// finalizes. Loss phase: 1 point/thread, one-pass shifted softmax.
// ---------------------------------------------------------------------------
__global__ __launch_bounds__(1024, 4) void mlp_loss_kernel(
    const float* __restrict__ latents,   // (B, 256)
    const float* __restrict__ eps,       // (S, B*N, 2)
    const float* __restrict__ realPts,   // (B, 2)
    const float* __restrict__ predMu,    // (B, 2)
    const float* __restrict__ predScale, // (B, 2)
    const float* __restrict__ W0, const float* __restrict__ b0,
    const float* __restrict__ W1, const float* __restrict__ b1,
    const float* __restrict__ W2, const float* __restrict__ b2,
    const float* __restrict__ W3, const float* __restrict__ b3,
    const float* __restrict__ W4, const float* __restrict__ b4,
    const float* __restrict__ Wt,        // (256,256) pre-transposed Wp
    const float* __restrict__ bp,        // (N,2) flat == bias[j]
    float* __restrict__ out) {
    __shared__ float  hbuf[2][RR][256];      // 8 KB activations (double buffer)
    __shared__ float  part[8][RR][256];      // 32 KB partials [q][row][col]
    __shared__ float2 sprm[NN];

    const int t  = threadIdx.x;
    const int q  = t >> 7;                   // K-eighth (MLP)
    const int c  = t & 127;                  // col-pair  (MLP)
    const int rL = t >> 8;                   // row (finalize + loss)
    const int j  = t & 255;                  // col (finalize + loss)
    const int brow = blockIdx.x * RR;

    if (t < NN) {
        float dv = DEV_MIN_F + (float)t * DEV_STEP_F;
        sprm[t] = make_float2(-0.5f / (dv * dv), -2.f * __logf(dv) - LOG2PI_F);
    }
    hbuf[0][rL][j] = latents[(brow + rL) * 256 + j];

    // prefetch loss-phase eps (2 VGPRs)
    const int nL = j >> 1;
    const int sL = j & 1;
    const float2 epv = ((const float2*)eps)[sL * (BB * NN) + (brow + rL) * NN + nL];

    const float* Ws[6] = {W0, W1, W2, W3, W4, Wt};
    const float* bs_[6] = {b0, b1, b2, b3, b4, bp};

    // prologue: bank A of layer 0 (16 dwordx2 in flight before first barrier)
    float2 wA[16], wB[16];
    {
        const float2* p = (const float2*)W0 + q * 32 * 128 + c;
        #pragma unroll
        for (int i = 0; i < 16; ++i) wA[i] = p[i * 128];
    }
    __syncthreads();

    int cur = 0;
    #pragma unroll
    for (int layer = 0; layer < 6; ++layer) {
        // issue bank B of this layer
        {
            const float2* p = (const float2*)Ws[layer] + (q * 32 + 16) * 128 + c;
            #pragma unroll
            for (int i = 0; i < 16; ++i) wB[i] = p[i * 128];
        }
        const float* __restrict__ h0p = &hbuf[cur][0][q * 32];
        const float* __restrict__ h1p = &hbuf[cur][1][q * 32];
        const float* __restrict__ h2p = &hbuf[cur][2][q * 32];
        const float* __restrict__ h3p = &hbuf[cur][3][q * 32];
        float2 acc0 = {0.f, 0.f}, acc1 = {0.f, 0.f};
        float2 acc2 = {0.f, 0.f}, acc3 = {0.f, 0.f};

        CONSUME(wA, 0)
        // issue bank A of NEXT layer before the barriers (stays in flight
        // through the partial-reduce barrier drain)
        if (layer < 5) {
            const float2* pn = (const float2*)Ws[layer + 1] + q * 32 * 128 + c;
            #pragma unroll
            for (int i = 0; i < 16; ++i) wA[i] = pn[i * 128];
        }
        CONSUME(wB, 16)

        ((float2*)&part[q][0][0])[c] = acc0;
        ((float2*)&part[q][1][0])[c] = acc1;
        ((float2*)&part[q][2][0])[c] = acc2;
        ((float2*)&part[q][3][0])[c] = acc3;
        __syncthreads();

        float val = 0.f;
        #pragma unroll
        for (int p = 0; p < 8; ++p) val += part[p][rL][j];
        val += bs_[layer][j];
        if (layer == 5) val += 0.5f;
        else            val = fmaxf(val, 0.f);
        hbuf[cur ^ 1][rL][j] = val;
        __syncthreads();
        cur ^= 1;
    }

    // ---- loss phase: mu for row (brow+rL) sits in hbuf[cur][rL] ----
    const float* __restrict__ muL = &hbuf[cur][rL][0];  // wave-uniform row
    const int b = brow + rL;
    const int n = nL, s = sL;
    const float devn = DEV_MIN_F + (float)n * DEV_STEP_F;
    const float2 prn = sprm[n];

    const float mux = muL[2 * n], muy = muL[2 * n + 1];
    const float px = fmaf(devn, epv.x, mux);
    const float py = fmaf(devn, epv.y, muy);

    // sampled
    ((float2*)out)[(size_t)(s * NN + n) * BB + b] = make_float2(px, py);

    // hoist global loads above the softmax loop (latency overlapped)
    const float pmx = predMu[b * 2],    pmy = predMu[b * 2 + 1];
    const float psx = predScale[b * 2], psy = predScale[b * 2 + 1];
    const float rx  = realPts[b * 2],   ry  = realPts[b * 2 + 1];

    // lossB: one-pass shifted softmax over 128 modes
    float sum0 = 0.f, sum1 = 0.f;
    #pragma unroll 4
    for (int m = 0; m < NN; m += 2) {
        float4 mm = *(const float4*)&muL[2 * m];
        float4 pr = *(const float4*)&sprm[m];
        float dx0 = px - mm.x, dy0 = py - mm.y;
        float lb0 = fmaf(fmaf(dx0, dx0, dy0 * dy0), pr.x, pr.y);
        sum0 += __expf(lb0 - SHIFT_F);
        float dx1 = px - mm.z, dy1 = py - mm.w;
        float lb1 = fmaf(fmaf(dx1, dx1, dy1 * dy1), pr.z, pr.w);
        sum1 += __expf(lb1 - SHIFT_F);
    }
    float dxd = devn * epv.x, dyd = devn * epv.y;
    float lbd = fmaf(fmaf(dxd, dxd, dyd * dyd), prn.x, prn.y);
    float ed  = __expf(lbd - SHIFT_F);
    float diag = ed / (sum0 + sum1);
    float lbv = (1.f - diag) * (1.f - diag);
    out[OFF_B + (size_t)b * (NN * SS) + j] = lbv;

    // lossA / genLoss under predicted dist
    float zx = (px - pmx) / psx, zy = (py - pmy) / psy;
    float la = -0.5f * (zx * zx + zy * zy) - __logf(psx) - __logf(psy) - LOG2PI_F;
    float aa = 1.f / (1.f + __expf(la));
    float termA = LOG1P_HALF - log1pf(aa);
    termA = termA * termA;
    float gg = 1.f / (1.f + __expf(-la));

    // realLoss
    float drx = rx - mux, dry = ry - muy;
    float lr = fmaf(fmaf(drx, drx, dry * dry), prn.x, prn.y);
    float rl = 1.f / (1.f + __expf(-lr));

    float termA_sum = termA + __shfl_xor(termA, 1);
    float gg_sum    = gg + __shfl_xor(gg, 1);
    if (s == 0) {
        out[OFF_GEN  + (size_t)b * NN + n] = 0.5f * gg_sum * (1.f - rl);
        out[OFF_REAL + (size_t)b * NN + n] = rl;
        out[OFF_A    + (size_t)b * NN + n] = 0.5f * termA_sum;
    }
}

// ---------------------------------------------------------------------------
extern "C" void kernel_launch(void* const* d_in, const int* in_sizes, int n_in,
                              void* d_out, int out_size, void* d_ws, size_t ws_size,
                              hipStream_t stream) {
    const float* latents   = (const float*)d_in[0];
    const float* realPts   = (const float*)d_in[1];
    const float* predMu    = (const float*)d_in[2];
    const float* predScale = (const float*)d_in[3];
    const float* eps       = (const float*)d_in[4];
    const float* W0 = (const float*)d_in[5];
    const float* b0 = (const float*)d_in[6];
    const float* W1 = (const float*)d_in[7];
    const float* b1 = (const float*)d_in[8];
    const float* W2 = (const float*)d_in[9];
    const float* b2 = (const float*)d_in[10];
    const float* W3 = (const float*)d_in[11];
    const float* b3 = (const float*)d_in[12];
    const float* W4 = (const float*)d_in[13];
    const float* b4 = (const float*)d_in[14];
    const float* Wp = (const float*)d_in[15];
    const float* bp = (const float*)d_in[16];

    float* Wtp = (float*)d_ws;  // 256 KB

    transpose_wp_kernel<<<dim3(256), dim3(256), 0, stream>>>(Wp, Wtp);
    mlp_loss_kernel<<<dim3(BB / RR), dim3(1024), 0, stream>>>(
        latents, eps, realPts, predMu, predScale,
        W0, b0, W1, b1, W2, b2, W3, b3, W4, b4, Wtp, bp, (float*)d_out);
}

// Round 7
// 125.496 us; speedup vs baseline: 1.4105x; 1.0032x over previous
//
#include <hip/hip_runtime.h>
#include <math.h>

#define BB   1024
#define HH   256
#define NN   128
#define SS   2
#define RR   4
#define LOG2PI_F 1.8378770664093453f
#define DEV_MIN_F 0.001f
#define DEV_STEP_F 7.08661417322835e-05f   // (0.01-0.001)/127
#define LOG1P_HALF 0.40546510810816438f    // log1p(0.5)
#define SHIFT_F 12.0f                       // > max lb = -2ln(0.001)-log2pi = 11.98

#define OFF_GEN  524288
#define OFF_REAL 655360
#define OFF_A    786432
#define OFF_B    917504

// ---- compiler-proof W prefetch machinery --------------------------------
// Volatile asm loads preserve mutual program order (cannot be sunk); each
// gate ties the bank's registers so consuming FMAs must follow the waitcnt.
// EVERY issued load is gated before its registers die (no dummy loads!) --
// otherwise the allocator reuses the dest VGPRs and the in-flight load
// clobbers them asynchronously (round-6 failure).
#define GLD2(dst, ptr, OFS) \
    asm volatile("global_load_dwordx2 %0, %1, off offset:" OFS \
                 : "=v"(dst) : "v"(ptr))

#define LOADBANK(S, P)                                            \
    {                                                             \
        const float* _pp = (P);                                   \
        GLD2(S[0], _pp, "-4096"); GLD2(S[1], _pp, "-3072");       \
        GLD2(S[2], _pp, "-2048"); GLD2(S[3], _pp, "-1024");       \
        GLD2(S[4], _pp, "0");     GLD2(S[5], _pp, "1024");        \
        GLD2(S[6], _pp, "2048");  GLD2(S[7], _pp, "3072");        \
    }

#define GATEN(S, CNT)                                                      \
    asm volatile("s_waitcnt vmcnt(" CNT ")"                                \
                 : "+v"(S[0]), "+v"(S[1]), "+v"(S[2]), "+v"(S[3]),         \
                   "+v"(S[4]), "+v"(S[5]), "+v"(S[6]), "+v"(S[7]))

// lgkm-only barrier: does NOT drain vmcnt -> prefetched banks survive
#define BAR_LDS()                                                 \
    {                                                             \
        asm volatile("s_waitcnt lgkmcnt(0)" ::: "memory");        \
        __builtin_amdgcn_s_barrier();                             \
        asm volatile("" ::: "memory");                            \
    }

// ---------------------------------------------------------------------------
__global__ __launch_bounds__(256) void transpose_wp_kernel(
    const float* __restrict__ Wp, float* __restrict__ Wt) {
    const int k = blockIdx.x;
    const int j = threadIdx.x;
    Wt[k * 256 + j] = Wp[(j >> 1) * 512 + k * 2 + (j & 1)];
}

// ---------------------------------------------------------------------------
// Fused MLP + losses, 256 blocks x 1024 threads, 4 batch rows/block.
// MLP thread = (q = t>>7 K-eighth, c = t&127 col-pair). 24 W-banks
// (6 layers x 4), 8 dwordx2 each, pipelined 2 banks deep via volatile asm.
// Gates: banks 0-21 -> vmcnt(16); bank 22 -> vmcnt(8); bank 23 -> vmcnt(0)
// (exact tail counts; nothing asm-issued outstanding after the pipeline).
// ---------------------------------------------------------------------------
__global__ __launch_bounds__(1024, 4) void mlp_loss_kernel(
    const float* __restrict__ latents, const float* __restrict__ eps,
    const float* __restrict__ realPts, const float* __restrict__ predMu,
    const float* __restrict__ predScale,
    const float* __restrict__ W0, const float* __restrict__ b0,
    const float* __restrict__ W1, const float* __restrict__ b1,
    const float* __restrict__ W2, const float* __restrict__ b2,
    const float* __restrict__ W3, const float* __restrict__ b3,
    const float* __restrict__ W4, const float* __restrict__ b4,
    const float* __restrict__ Wt, const float* __restrict__ bp,
    float* __restrict__ out) {
    __shared__ float  hbuf[2][RR][256];   // 8 KB
    __shared__ float  part[8][RR][256];   // 32 KB
    __shared__ float  sbias[6][256];      // 6 KB
    __shared__ float2 sprm[NN];           // 1 KB

    const int t  = threadIdx.x;
    const int q  = t >> 7;
    const int c  = t & 127;
    const int rL = t >> 8;
    const int j  = t & 255;
    const int brow = blockIdx.x * RR;

    if (t < NN) {
        float dv = DEV_MIN_F + (float)t * DEV_STEP_F;
        sprm[t] = make_float2(-0.5f / (dv * dv), -2.f * __logf(dv) - LOG2PI_F);
    }
    hbuf[0][rL][j] = latents[(brow + rL) * 256 + j];
    // biases -> LDS (no vmem inside the pipeline)
    #pragma unroll
    for (int ii = 0; ii < 2; ++ii) {
        int idx = t + ii * 1024;
        if (idx < 1536) {
            int Lb = idx >> 8, jj = idx & 255;
            const float* bsrc = (Lb == 0) ? b0 : (Lb == 1) ? b1 : (Lb == 2) ? b2
                              : (Lb == 3) ? b3 : (Lb == 4) ? b4 : bp;
            sbias[Lb][jj] = bsrc[jj];
        }
    }
    // preload loss-phase inputs (used only after the pipeline)
    const int nL = j >> 1, sL = j & 1;
    const int b = brow + rL;
    const float2 epv = ((const float2*)eps)[sL * (BB * NN) + b * NN + nL];
    const float2 pm  = ((const float2*)predMu)[b];
    const float2 ps  = ((const float2*)predScale)[b];
    const float2 rp  = ((const float2*)realPts)[b];

    BAR_LDS();

    const float* Wsrc[6] = {W0, W1, W2, W3, W4, Wt};
    const int coff = 2 * c + 1024;        // centered (+4096 B) thread column base

    float2 bk[3][8];
    // prologue: banks 0,1 (layer 0)
    LOADBANK(bk[0], W0 + (q * 32 + 0) * 256 + coff);
    LOADBANK(bk[1], W0 + (q * 32 + 8) * 256 + coff);

    #pragma unroll
    for (int L = 0; L < 6; ++L) {
        const int cur = L & 1;
        float2 acc0 = {0.f, 0.f}, acc1 = {0.f, 0.f};
        float2 acc2 = {0.f, 0.f}, acc3 = {0.f, 0.f};
        #pragma unroll
        for (int i = 0; i < 4; ++i) {
            const int gb = L * 4 + i;
            const int nb = gb + 2;
            if (nb < 24) {
                LOADBANK(bk[nb % 3],
                         Wsrc[nb >> 2] + (q * 32 + (nb & 3) * 8) * 256 + coff);
            }
            // exact-tail gates: always completes bank gb; bank 23's gate
            // drains vmcnt to 0 so nothing asm-issued survives the pipeline
            if (gb <= 21)      { GATEN(bk[gb % 3], "16"); }
            else if (gb == 22) { GATEN(bk[gb % 3], "8");  }
            else               { GATEN(bk[gb % 3], "0");  }
            const int kb = q * 32 + i * 8;
            float4 hA0 = *(const float4*)&hbuf[cur][0][kb];
            float4 hB0 = *(const float4*)&hbuf[cur][0][kb + 4];
            float4 hA1 = *(const float4*)&hbuf[cur][1][kb];
            float4 hB1 = *(const float4*)&hbuf[cur][1][kb + 4];
            float4 hA2 = *(const float4*)&hbuf[cur][2][kb];
            float4 hB2 = *(const float4*)&hbuf[cur][2][kb + 4];
            float4 hA3 = *(const float4*)&hbuf[cur][3][kb];
            float4 hB3 = *(const float4*)&hbuf[cur][3][kb + 4];
            const float2* S = bk[gb % 3];
            #pragma unroll
            for (int kk = 0; kk < 8; ++kk) {
                float2 wv = S[kk];
                float h0 = (kk < 4) ? (&hA0.x)[kk] : (&hB0.x)[kk - 4];
                float h1 = (kk < 4) ? (&hA1.x)[kk] : (&hB1.x)[kk - 4];
                float h2 = (kk < 4) ? (&hA2.x)[kk] : (&hB2.x)[kk - 4];
                float h3 = (kk < 4) ? (&hA3.x)[kk] : (&hB3.x)[kk - 4];
                acc0.x = fmaf(h0, wv.x, acc0.x); acc0.y = fmaf(h0, wv.y, acc0.y);
                acc1.x = fmaf(h1, wv.x, acc1.x); acc1.y = fmaf(h1, wv.y, acc1.y);
                acc2.x = fmaf(h2, wv.x, acc2.x); acc2.y = fmaf(h2, wv.y, acc2.y);
                acc3.x = fmaf(h3, wv.x, acc3.x); acc3.y = fmaf(h3, wv.y, acc3.y);
            }
        }
        ((float2*)&part[q][0][0])[c] = acc0;
        ((float2*)&part[q][1][0])[c] = acc1;
        ((float2*)&part[q][2][0])[c] = acc2;
        ((float2*)&part[q][3][0])[c] = acc3;
        BAR_LDS();
        float val = 0.f;
        #pragma unroll
        for (int p = 0; p < 8; ++p) val += part[p][rL][j];
        val += sbias[L][j];
        if (L == 5) val += 0.5f;
        else        val = fmaxf(val, 0.f);
        hbuf[cur ^ 1][rL][j] = val;
        BAR_LDS();
    }

    // ---- loss phase: mu in hbuf[0][rL] ----
    const float* __restrict__ muL = &hbuf[0][rL][0];
    const int n = nL, s = sL;
    const float devn = DEV_MIN_F + (float)n * DEV_STEP_F;
    const float2 prn = sprm[n];

    const float mux = muL[2 * n], muy = muL[2 * n + 1];
    const float px = fmaf(devn, epv.x, mux);
    const float py = fmaf(devn, epv.y, muy);

    ((float2*)out)[(size_t)(s * NN + n) * BB + b] = make_float2(px, py);

    float sum0 = 0.f, sum1 = 0.f;
    #pragma unroll 4
    for (int m = 0; m < NN; m += 2) {
        float4 mm = *(const float4*)&muL[2 * m];
        float4 pr = *(const float4*)&sprm[m];
        float dx0 = px - mm.x, dy0 = py - mm.y;
        float lb0 = fmaf(fmaf(dx0, dx0, dy0 * dy0), pr.x, pr.y);
        sum0 += __expf(lb0 - SHIFT_F);
        float dx1 = px - mm.z, dy1 = py - mm.w;
        float lb1 = fmaf(fmaf(dx1, dx1, dy1 * dy1), pr.z, pr.w);
        sum1 += __expf(lb1 - SHIFT_F);
    }
    float dxd = devn * epv.x, dyd = devn * epv.y;
    float lbd = fmaf(fmaf(dxd, dxd, dyd * dyd), prn.x, prn.y);
    float ed  = __expf(lbd - SHIFT_F);
    float diag = ed / (sum0 + sum1);
    float lbv = (1.f - diag) * (1.f - diag);
    out[OFF_B + (size_t)b * (NN * SS) + j] = lbv;

    float zx = (px - pm.x) / ps.x, zy = (py - pm.y) / ps.y;
    float la = -0.5f * (zx * zx + zy * zy) - __logf(ps.x) - __logf(ps.y) - LOG2PI_F;
    float aa = 1.f / (1.f + __expf(la));
    float termA = LOG1P_HALF - log1pf(aa);
    termA = termA * termA;
    float gg = 1.f / (1.f + __expf(-la));

    float drx = rp.x - mux, dry = rp.y - muy;
    float lr = fmaf(fmaf(drx, drx, dry * dry), prn.x, prn.y);
    float rl = 1.f / (1.f + __expf(-lr));

    float termA_sum = termA + __shfl_xor(termA, 1);
    float gg_sum    = gg + __shfl_xor(gg, 1);
    if (s == 0) {
        out[OFF_GEN  + (size_t)b * NN + n] = 0.5f * gg_sum * (1.f - rl);
        out[OFF_REAL + (size_t)b * NN + n] = rl;
        out[OFF_A    + (size_t)b * NN + n] = 0.5f * termA_sum;
    }
}

// ---------------------------------------------------------------------------
extern "C" void kernel_launch(void* const* d_in, const int* in_sizes, int n_in,
                              void* d_out, int out_size, void* d_ws, size_t ws_size,
                              hipStream_t stream) {
    const float* latents   = (const float*)d_in[0];
    const float* realPts   = (const float*)d_in[1];
    const float* predMu    = (const float*)d_in[2];
    const float* predScale = (const float*)d_in[3];
    const float* eps       = (const float*)d_in[4];
    const float* W0 = (const float*)d_in[5];
    const float* b0 = (const float*)d_in[6];
    const float* W1 = (const float*)d_in[7];
    const float* b1 = (const float*)d_in[8];
    const float* W2 = (const float*)d_in[9];
    const float* b2 = (const float*)d_in[10];
    const float* W3 = (const float*)d_in[11];
    const float* b3 = (const float*)d_in[12];
    const float* W4 = (const float*)d_in[13];
    const float* b4 = (const float*)d_in[14];
    const float* Wp = (const float*)d_in[15];
    const float* bp = (const float*)d_in[16];

    float* Wtp = (float*)d_ws;  // 256 KB

    transpose_wp_kernel<<<dim3(256), dim3(256), 0, stream>>>(Wp, Wtp);
    mlp_loss_kernel<<<dim3(BB / RR), dim3(1024), 0, stream>>>(
        latents, eps, realPts, predMu, predScale,
        W0, b0, W1, b1, W2, b2, W3, b3, W4, b4, Wtp, bp, (float*)d_out);
}

// Round 9
// 120.465 us; speedup vs baseline: 1.4694x; 1.0418x over previous
//
#include <hip/hip_runtime.h>
#include <math.h>

#define BB   1024
#define HH   256
#define NN   128
#define SS   2
#define RR   4
#define LOG2PI_F 1.8378770664093453f
#define DEV_MIN_F 0.001f
#define DEV_STEP_F 7.08661417322835e-05f   // (0.01-0.001)/127
#define LOG1P_HALF 0.40546510810816438f    // log1p(0.5)
#define SHIFT_F 12.0f                       // > max lb = -2ln(0.001)-log2pi = 11.98

#define OFF_GEN  524288
#define OFF_REAL 655360
#define OFF_A    786432
#define OFF_B    917504

typedef float f4_t __attribute__((ext_vector_type(4)));

#define FMA4(ACC, HS, WV)                                         \
    {                                                             \
        ACC.x = fmaf(HS, WV.x, ACC.x);                            \
        ACC.y = fmaf(HS, WV.y, ACC.y);                            \
        ACC.z = fmaf(HS, WV.z, ACC.z);                            \
        ACC.w = fmaf(HS, WV.w, ACC.w);                            \
    }

// ---------------------------------------------------------------------------
__global__ __launch_bounds__(256) void transpose_wp_kernel(
    const float* __restrict__ Wp, float* __restrict__ Wt) {
    const int k = blockIdx.x;
    const int j = threadIdx.x;
    Wt[k * 256 + j] = Wp[(j >> 1) * 512 + k * 2 + (j & 1)];
}

// ---------------------------------------------------------------------------
// Fused MLP + losses, 256 blocks x 1024 threads, 4 batch rows/block.
// NO asm pipeline (round 7 measured it worth 0; rounds 6/8 showed the
// register-clobber hazard). Plain f4_t W loads -> global_load_dwordx4,
// compiler-scheduled.
// MLP thread = (q = t>>6: 16 K-slices of 16, c = t&63: col-quad). W read
// exactly once per CU per layer. Partials: q<8 write part[8][4][256]
// (32 KB), q>=8 RMW-add, then 8-way b32 finalize per (row,col) thread.
// Softmax: 4-way mode split across the (n-pair x s) lane quad; each lane
// scans 32 modes for all 4 quad points; butterfly all-reduce (xor 1,2).
// ---------------------------------------------------------------------------
__global__ __launch_bounds__(1024, 4) void mlp_loss_kernel(
    const float* __restrict__ latents, const float* __restrict__ eps,
    const float* __restrict__ realPts, const float* __restrict__ predMu,
    const float* __restrict__ predScale,
    const float* __restrict__ W0, const float* __restrict__ b0,
    const float* __restrict__ W1, const float* __restrict__ b1,
    const float* __restrict__ W2, const float* __restrict__ b2,
    const float* __restrict__ W3, const float* __restrict__ b3,
    const float* __restrict__ W4, const float* __restrict__ b4,
    const float* __restrict__ Wt, const float* __restrict__ bp,
    float* __restrict__ out) {
    __shared__ __align__(16) float hb[RR][256];       // 4 KB activations
    __shared__ __align__(16) float part[8][RR][256];  // 32 KB partials
    __shared__ float2 sprm[NN];                       // 1 KB

    const int t  = threadIdx.x;
    const int q  = t >> 6;                // K-slice 0..15 (wave-uniform)
    const int c  = t & 63;                // col-quad base j4 = 4c
    const int rL = t >> 8;                // row (finalize + loss)
    const int j  = t & 255;               // col (finalize + loss)
    const int brow = blockIdx.x * RR;

    if (t < NN) {
        float dv = DEV_MIN_F + (float)t * DEV_STEP_F;
        sprm[t] = make_float2(-0.5f / (dv * dv), -2.f * __logf(dv) - LOG2PI_F);
    }
    hb[rL][j] = latents[(brow + rL) * 256 + j];

    // biases in 6 VGPRs
    float biasv[6];
    biasv[0] = b0[j]; biasv[1] = b1[j]; biasv[2] = b2[j];
    biasv[3] = b3[j]; biasv[4] = b4[j]; biasv[5] = bp[j];

    // eps preloaded (needed immediately at loss start)
    const int nL = j >> 1, sL = j & 1;
    const int b = brow + rL;
    const float2 epv = ((const float2*)eps)[sL * (BB * NN) + b * NN + nL];

    __syncthreads();

    const float* Wsrc[6] = {W0, W1, W2, W3, W4, Wt};

    #pragma unroll
    for (int L = 0; L < 6; ++L) {
        const float* __restrict__ Wb = Wsrc[L] + (q * 16) * 256 + 4 * c;
        f4_t acc[4];
        #pragma unroll
        for (int r = 0; r < 4; ++r) acc[r] = (f4_t)0.f;

        #pragma unroll
        for (int i = 0; i < 4; ++i) {
            f4_t w0 = *(const f4_t*)(Wb + (i * 4 + 0) * 256);
            f4_t w1 = *(const f4_t*)(Wb + (i * 4 + 1) * 256);
            f4_t w2 = *(const f4_t*)(Wb + (i * 4 + 2) * 256);
            f4_t w3 = *(const f4_t*)(Wb + (i * 4 + 3) * 256);
            const int kb = q * 16 + i * 4;
            #pragma unroll
            for (int r = 0; r < 4; ++r) {
                f4_t hv = *(const f4_t*)&hb[r][kb];
                FMA4(acc[r], hv.x, w0);
                FMA4(acc[r], hv.y, w1);
                FMA4(acc[r], hv.z, w2);
                FMA4(acc[r], hv.w, w3);
            }
        }

        // two-step 16 -> 8 partial combine (wave-uniform branches)
        if (q < 8) {
            #pragma unroll
            for (int r = 0; r < 4; ++r)
                *(f4_t*)&part[q][r][4 * c] = acc[r];
        }
        __syncthreads();
        if (q >= 8) {
            #pragma unroll
            for (int r = 0; r < 4; ++r) {
                f4_t tmp = *(const f4_t*)&part[q - 8][r][4 * c];
                acc[r] += tmp;
                *(f4_t*)&part[q - 8][r][4 * c] = acc[r];
            }
        }
        __syncthreads();

        float val = part[0][rL][j] + part[1][rL][j] + part[2][rL][j] +
                    part[3][rL][j] + part[4][rL][j] + part[5][rL][j] +
                    part[6][rL][j] + part[7][rL][j];
        val += biasv[L];
        if (L == 5) val += 0.5f;
        else        val = fmaxf(val, 0.f);
        hb[rL][j] = val;   // safe: hb reads all completed before 1st barrier
        __syncthreads();
    }

    // ---- loss phase: mu for row (brow+rL) in hb[rL] ----
    const float* __restrict__ muL = &hb[rL][0];
    const int n = nL, s = sL;
    const float devn = DEV_MIN_F + (float)n * DEV_STEP_F;
    const float2 prn = sprm[n];

    const float mux = muL[2 * n], muy = muL[2 * n + 1];
    const float px = fmaf(devn, epv.x, mux);
    const float py = fmaf(devn, epv.y, muy);

    ((float2*)out)[(size_t)(s * NN + n) * BB + b] = make_float2(px, py);

    // loss-tail inputs loaded here (softmax below hides the latency)
    const float2 pm = ((const float2*)predMu)[b];
    const float2 ps = ((const float2*)predScale)[b];
    const float2 rp = ((const float2*)realPts)[b];

    // gather the 4 quad points (same row; j differing in bits 0-1)
    const int me = t & 3;
    float x1 = __shfl_xor(px, 1), y1 = __shfl_xor(py, 1);
    float x2 = __shfl_xor(px, 2), y2 = __shfl_xor(py, 2);
    float x3 = __shfl_xor(px, 3), y3 = __shfl_xor(py, 3);
    float PX0 = (me == 0) ? px : (me == 1) ? x1 : (me == 2) ? x2 : x3;
    float PY0 = (me == 0) ? py : (me == 1) ? y1 : (me == 2) ? y2 : y3;
    float PX1 = (me == 1) ? px : (me == 0) ? x1 : (me == 3) ? x2 : x3;
    float PY1 = (me == 1) ? py : (me == 0) ? y1 : (me == 3) ? y2 : y3;
    float PX2 = (me == 2) ? px : (me == 3) ? x1 : (me == 0) ? x2 : x3;
    float PY2 = (me == 2) ? py : (me == 3) ? y1 : (me == 0) ? y2 : y3;
    float PX3 = (me == 3) ? px : (me == 2) ? x1 : (me == 1) ? x2 : x3;
    float PY3 = (me == 3) ? py : (me == 2) ? y1 : (me == 1) ? y2 : y3;

    // lane me scans modes {8*mi + 2*me, +1 : mi=0..15} for all 4 points
    float S0 = 0.f, S1 = 0.f, S2 = 0.f, S3 = 0.f;
    #pragma unroll 4
    for (int mi = 0; mi < 16; ++mi) {
        f4_t mm = *(const f4_t*)&muL[16 * mi + 4 * me];
        f4_t pr = *(const f4_t*)((const float*)sprm + 16 * mi + 4 * me);
        float dx, dy, lb;
        dx = PX0 - mm.x; dy = PY0 - mm.y;
        lb = fmaf(fmaf(dx, dx, dy * dy), pr.x, pr.y); S0 += __expf(lb - SHIFT_F);
        dx = PX1 - mm.x; dy = PY1 - mm.y;
        lb = fmaf(fmaf(dx, dx, dy * dy), pr.x, pr.y); S1 += __expf(lb - SHIFT_F);
        dx = PX2 - mm.x; dy = PY2 - mm.y;
        lb = fmaf(fmaf(dx, dx, dy * dy), pr.x, pr.y); S2 += __expf(lb - SHIFT_F);
        dx = PX3 - mm.x; dy = PY3 - mm.y;
        lb = fmaf(fmaf(dx, dx, dy * dy), pr.x, pr.y); S3 += __expf(lb - SHIFT_F);
        dx = PX0 - mm.z; dy = PY0 - mm.w;
        lb = fmaf(fmaf(dx, dx, dy * dy), pr.z, pr.w); S0 += __expf(lb - SHIFT_F);
        dx = PX1 - mm.z; dy = PY1 - mm.w;
        lb = fmaf(fmaf(dx, dx, dy * dy), pr.z, pr.w); S1 += __expf(lb - SHIFT_F);
        dx = PX2 - mm.z; dy = PY2 - mm.w;
        lb = fmaf(fmaf(dx, dx, dy * dy), pr.z, pr.w); S2 += __expf(lb - SHIFT_F);
        dx = PX3 - mm.z; dy = PY3 - mm.w;
        lb = fmaf(fmaf(dx, dx, dy * dy), pr.z, pr.w); S3 += __expf(lb - SHIFT_F);
    }
    // butterfly all-reduce across the quad
    S0 += __shfl_xor(S0, 1); S1 += __shfl_xor(S1, 1);
    S2 += __shfl_xor(S2, 1); S3 += __shfl_xor(S3, 1);
    S0 += __shfl_xor(S0, 2); S1 += __shfl_xor(S1, 2);
    S2 += __shfl_xor(S2, 2); S3 += __shfl_xor(S3, 2);
    float sum = (me == 0) ? S0 : (me == 1) ? S1 : (me == 2) ? S2 : S3;

    // diagonal closed-form: dx = devn*eps -> lb = prn.x*devn^2*|eps|^2 + prn.y
    float dxd = devn * epv.x, dyd = devn * epv.y;
    float lbd = fmaf(fmaf(dxd, dxd, dyd * dyd), prn.x, prn.y);
    float ed  = __expf(lbd - SHIFT_F);
    float diag = ed / sum;
    float lbv = (1.f - diag) * (1.f - diag);
    out[OFF_B + (size_t)b * (NN * SS) + j] = lbv;

    float zx = (px - pm.x) / ps.x, zy = (py - pm.y) / ps.y;
    float la = -0.5f * (zx * zx + zy * zy) - __logf(ps.x) - __logf(ps.y) - LOG2PI_F;
    float aa = 1.f / (1.f + __expf(la));
    float termA = LOG1P_HALF - log1pf(aa);
    termA = termA * termA;
    float gg = 1.f / (1.f + __expf(-la));

    float drx = rp.x - mux, dry = rp.y - muy;
    float lr = fmaf(fmaf(drx, drx, dry * dry), prn.x, prn.y);
    float rl = 1.f / (1.f + __expf(-lr));

    float termA_sum = termA + __shfl_xor(termA, 1);
    float gg_sum    = gg + __shfl_xor(gg, 1);
    if (s == 0) {
        out[OFF_GEN  + (size_t)b * NN + n] = 0.5f * gg_sum * (1.f - rl);
        out[OFF_REAL + (size_t)b * NN + n] = rl;
        out[OFF_A    + (size_t)b * NN + n] = 0.5f * termA_sum;
    }
}

// ---------------------------------------------------------------------------
extern "C" void kernel_launch(void* const* d_in, const int* in_sizes, int n_in,
                              void* d_out, int out_size, void* d_ws, size_t ws_size,
                              hipStream_t stream) {
    const float* latents   = (const float*)d_in[0];
    const float* realPts   = (const float*)d_in[1];
    const float* predMu    = (const float*)d_in[2];
    const float* predScale = (const float*)d_in[3];
    const float* eps       = (const float*)d_in[4];
    const float* W0 = (const float*)d_in[5];
    const float* b0 = (const float*)d_in[6];
    const float* W1 = (const float*)d_in[7];
    const float* b1 = (const float*)d_in[8];
    const float* W2 = (const float*)d_in[9];
    const float* b2 = (const float*)d_in[10];
    const float* W3 = (const float*)d_in[11];
    const float* b3 = (const float*)d_in[12];
    const float* W4 = (const float*)d_in[13];
    const float* b4 = (const float*)d_in[14];
    const float* Wp = (const float*)d_in[15];
    const float* bp = (const float*)d_in[16];

    float* Wtp = (float*)d_ws;  // 256 KB

    transpose_wp_kernel<<<dim3(256), dim3(256), 0, stream>>>(Wp, Wtp);
    mlp_loss_kernel<<<dim3(BB / RR), dim3(1024), 0, stream>>>(
        latents, eps, realPts, predMu, predScale,
        W0, b0, W1, b1, W2, b2, W3, b3, W4, b4, Wtp, bp, (float*)d_out);
}

// Round 10
// 117.337 us; speedup vs baseline: 1.5085x; 1.0267x over previous
//
#include <hip/hip_runtime.h>
#include <math.h>

#define BB   1024
#define HH   256
#define NN   128
#define SS   2
#define RR   4
#define LOG2PI_F 1.8378770664093453f
#define DEV_MIN_F 0.001f
#define DEV_STEP_F 7.08661417322835e-05f   // (0.01-0.001)/127
#define LOG1P_HALF 0.40546510810816438f    // log1p(0.5)
#define SHIFT_F 12.0f                       // > max lb = -2ln(0.001)-log2pi = 11.98

#define OFF_GEN  524288
#define OFF_REAL 655360
#define OFF_A    786432
#define OFF_B    917504

typedef float f4_t __attribute__((ext_vector_type(4)));

#define FMA4(ACC, HS, WV)                                         \
    {                                                             \
        ACC.x = fmaf(HS, WV.x, ACC.x);                            \
        ACC.y = fmaf(HS, WV.y, ACC.y);                            \
        ACC.z = fmaf(HS, WV.z, ACC.z);                            \
        ACC.w = fmaf(HS, WV.w, ACC.w);                            \
    }

// ---------------------------------------------------------------------------
__global__ __launch_bounds__(256) void transpose_wp_kernel(
    const float* __restrict__ Wp, float* __restrict__ Wt) {
    const int k = blockIdx.x;
    const int j = threadIdx.x;
    Wt[k * 256 + j] = Wp[(j >> 1) * 512 + k * 2 + (j & 1)];
}

// ---------------------------------------------------------------------------
// Fused MLP + losses, 256 blocks x 1024 threads, 4 batch rows/block.
// MLP thread = (q = t>>6 == wave id: 16 K-slices of 16, c = t&63: col-quad).
// W (f4 loads, dwordx4) read exactly once per CU per layer; hb reads are
// wave-uniform b128 BROADCASTS (q == wave -> free).
// Partials: single-step — all 16 waves write part[16][4][256] (64 KB),
// one barrier, finalize thread (rL,j) sums 16 stride-1 b32 (conflict-free).
// 2 barriers/layer (was 3 + RMW traffic in round 9).
// Softmax: 4-way mode split across the (n-pair x s) lane quad; butterfly
// all-reduce (xor 1,2).
// ---------------------------------------------------------------------------
__global__ __launch_bounds__(1024, 4) void mlp_loss_kernel(
    const float* __restrict__ latents, const float* __restrict__ eps,
    const float* __restrict__ realPts, const float* __restrict__ predMu,
    const float* __restrict__ predScale,
    const float* __restrict__ W0, const float* __restrict__ b0,
    const float* __restrict__ W1, const float* __restrict__ b1,
    const float* __restrict__ W2, const float* __restrict__ b2,
    const float* __restrict__ W3, const float* __restrict__ b3,
    const float* __restrict__ W4, const float* __restrict__ b4,
    const float* __restrict__ Wt, const float* __restrict__ bp,
    float* __restrict__ out) {
    __shared__ __align__(16) float hb[RR][256];        // 4 KB activations
    __shared__ __align__(16) float part[16][RR][256];  // 64 KB partials
    __shared__ float2 sprm[NN];                        // 1 KB

    const int t  = threadIdx.x;
    const int q  = t >> 6;                // K-slice == wave id
    const int c  = t & 63;                // col-quad base j4 = 4c
    const int rL = t >> 8;                // row (finalize + loss)
    const int j  = t & 255;               // col (finalize + loss)
    const int brow = blockIdx.x * RR;

    if (t < NN) {
        float dv = DEV_MIN_F + (float)t * DEV_STEP_F;
        sprm[t] = make_float2(-0.5f / (dv * dv), -2.f * __logf(dv) - LOG2PI_F);
    }
    hb[rL][j] = latents[(brow + rL) * 256 + j];

    // biases in 6 VGPRs
    float biasv[6];
    biasv[0] = b0[j]; biasv[1] = b1[j]; biasv[2] = b2[j];
    biasv[3] = b3[j]; biasv[4] = b4[j]; biasv[5] = bp[j];

    // eps preloaded (needed immediately at loss start)
    const int nL = j >> 1, sL = j & 1;
    const int b = brow + rL;
    const float2 epv = ((const float2*)eps)[sL * (BB * NN) + b * NN + nL];

    __syncthreads();

    const float* Wsrc[6] = {W0, W1, W2, W3, W4, Wt};

    #pragma unroll
    for (int L = 0; L < 6; ++L) {
        const float* __restrict__ Wb = Wsrc[L] + (q * 16) * 256 + 4 * c;
        f4_t acc[4];
        #pragma unroll
        for (int r = 0; r < 4; ++r) acc[r] = (f4_t)0.f;

        #pragma unroll
        for (int i = 0; i < 4; ++i) {
            f4_t w0 = *(const f4_t*)(Wb + (i * 4 + 0) * 256);
            f4_t w1 = *(const f4_t*)(Wb + (i * 4 + 1) * 256);
            f4_t w2 = *(const f4_t*)(Wb + (i * 4 + 2) * 256);
            f4_t w3 = *(const f4_t*)(Wb + (i * 4 + 3) * 256);
            const int kb = q * 16 + i * 4;
            #pragma unroll
            for (int r = 0; r < 4; ++r) {
                f4_t hv = *(const f4_t*)&hb[r][kb];   // wave-uniform broadcast
                FMA4(acc[r], hv.x, w0);
                FMA4(acc[r], hv.y, w1);
                FMA4(acc[r], hv.z, w2);
                FMA4(acc[r], hv.w, w3);
            }
        }

        // single-step partial combine: every wave writes its own slot
        #pragma unroll
        for (int r = 0; r < 4; ++r)
            *(f4_t*)&part[q][r][4 * c] = acc[r];
        __syncthreads();

        // finalize: 16 stride-1 b32 reads (2 lanes/bank -> conflict-free)
        float v0 = part[0][rL][j]  + part[1][rL][j]  + part[2][rL][j]  + part[3][rL][j];
        float v1 = part[4][rL][j]  + part[5][rL][j]  + part[6][rL][j]  + part[7][rL][j];
        float v2 = part[8][rL][j]  + part[9][rL][j]  + part[10][rL][j] + part[11][rL][j];
        float v3 = part[12][rL][j] + part[13][rL][j] + part[14][rL][j] + part[15][rL][j];
        float val = (v0 + v1) + (v2 + v3);
        val += biasv[L];
        if (L == 5) val += 0.5f;
        else        val = fmaxf(val, 0.f);
        hb[rL][j] = val;   // safe: all hb broadcasts of this layer precede barrier-1
        __syncthreads();
    }

    // ---- loss phase: mu for row (brow+rL) in hb[rL] ----
    const float* __restrict__ muL = &hb[rL][0];
    const int n = nL, s = sL;
    const float devn = DEV_MIN_F + (float)n * DEV_STEP_F;
    const float2 prn = sprm[n];

    const float mux = muL[2 * n], muy = muL[2 * n + 1];
    const float px = fmaf(devn, epv.x, mux);
    const float py = fmaf(devn, epv.y, muy);

    ((float2*)out)[(size_t)(s * NN + n) * BB + b] = make_float2(px, py);

    // loss-tail inputs loaded here (softmax below hides the latency)
    const float2 pm = ((const float2*)predMu)[b];
    const float2 ps = ((const float2*)predScale)[b];
    const float2 rp = ((const float2*)realPts)[b];

    // gather the 4 quad points (same row; j differing in bits 0-1)
    const int me = t & 3;
    float x1 = __shfl_xor(px, 1), y1 = __shfl_xor(py, 1);
    float x2 = __shfl_xor(px, 2), y2 = __shfl_xor(py, 2);
    float x3 = __shfl_xor(px, 3), y3 = __shfl_xor(py, 3);
    float PX0 = (me == 0) ? px : (me == 1) ? x1 : (me == 2) ? x2 : x3;
    float PY0 = (me == 0) ? py : (me == 1) ? y1 : (me == 2) ? y2 : y3;
    float PX1 = (me == 1) ? px : (me == 0) ? x1 : (me == 3) ? x2 : x3;
    float PY1 = (me == 1) ? py : (me == 0) ? y1 : (me == 3) ? y2 : y3;
    float PX2 = (me == 2) ? px : (me == 3) ? x1 : (me == 0) ? x2 : x3;
    float PY2 = (me == 2) ? py : (me == 3) ? y1 : (me == 0) ? y2 : y3;
    float PX3 = (me == 3) ? px : (me == 2) ? x1 : (me == 1) ? x2 : x3;
    float PY3 = (me == 3) ? py : (me == 2) ? y1 : (me == 1) ? y2 : y3;

    // lane me scans modes {8*mi + 2*me, +1 : mi=0..15} for all 4 points
    float S0 = 0.f, S1 = 0.f, S2 = 0.f, S3 = 0.f;
    #pragma unroll 4
    for (int mi = 0; mi < 16; ++mi) {
        f4_t mm = *(const f4_t*)&muL[16 * mi + 4 * me];
        f4_t pr = *(const f4_t*)((const float*)sprm + 16 * mi + 4 * me);
        float dx, dy, lb;
        dx = PX0 - mm.x; dy = PY0 - mm.y;
        lb = fmaf(fmaf(dx, dx, dy * dy), pr.x, pr.y); S0 += __expf(lb - SHIFT_F);
        dx = PX1 - mm.x; dy = PY1 - mm.y;
        lb = fmaf(fmaf(dx, dx, dy * dy), pr.x, pr.y); S1 += __expf(lb - SHIFT_F);
        dx = PX2 - mm.x; dy = PY2 - mm.y;
        lb = fmaf(fmaf(dx, dx, dy * dy), pr.x, pr.y); S2 += __expf(lb - SHIFT_F);
        dx = PX3 - mm.x; dy = PY3 - mm.y;
        lb = fmaf(fmaf(dx, dx, dy * dy), pr.x, pr.y); S3 += __expf(lb - SHIFT_F);
        dx = PX0 - mm.z; dy = PY0 - mm.w;
        lb = fmaf(fmaf(dx, dx, dy * dy), pr.z, pr.w); S0 += __expf(lb - SHIFT_F);
        dx = PX1 - mm.z; dy = PY1 - mm.w;
        lb = fmaf(fmaf(dx, dx, dy * dy), pr.z, pr.w); S1 += __expf(lb - SHIFT_F);
        dx = PX2 - mm.z; dy = PY2 - mm.w;
        lb = fmaf(fmaf(dx, dx, dy * dy), pr.z, pr.w); S2 += __expf(lb - SHIFT_F);
        dx = PX3 - mm.z; dy = PY3 - mm.w;
        lb = fmaf(fmaf(dx, dx, dy * dy), pr.z, pr.w); S3 += __expf(lb - SHIFT_F);
    }
    // butterfly all-reduce across the quad
    S0 += __shfl_xor(S0, 1); S1 += __shfl_xor(S1, 1);
    S2 += __shfl_xor(S2, 1); S3 += __shfl_xor(S3, 1);
    S0 += __shfl_xor(S0, 2); S1 += __shfl_xor(S1, 2);
    S2 += __shfl_xor(S2, 2); S3 += __shfl_xor(S3, 2);
    float sum = (me == 0) ? S0 : (me == 1) ? S1 : (me == 2) ? S2 : S3;

    // diagonal closed-form: dx = devn*eps -> lb = prn.x*devn^2*|eps|^2 + prn.y
    float dxd = devn * epv.x, dyd = devn * epv.y;
    float lbd = fmaf(fmaf(dxd, dxd, dyd * dyd), prn.x, prn.y);
    float ed  = __expf(lbd - SHIFT_F);
    float diag = ed / sum;
    float lbv = (1.f - diag) * (1.f - diag);
    out[OFF_B + (size_t)b * (NN * SS) + j] = lbv;

    float zx = (px - pm.x) / ps.x, zy = (py - pm.y) / ps.y;
    float la = -0.5f * (zx * zx + zy * zy) - __logf(ps.x) - __logf(ps.y) - LOG2PI_F;
    float aa = 1.f / (1.f + __expf(la));
    float termA = LOG1P_HALF - log1pf(aa);
    termA = termA * termA;
    float gg = 1.f / (1.f + __expf(-la));

    float drx = rp.x - mux, dry = rp.y - muy;
    float lr = fmaf(fmaf(drx, drx, dry * dry), prn.x, prn.y);
    float rl = 1.f / (1.f + __expf(-lr));

    float termA_sum = termA + __shfl_xor(termA, 1);
    float gg_sum    = gg + __shfl_xor(gg, 1);
    if (s == 0) {
        out[OFF_GEN  + (size_t)b * NN + n] = 0.5f * gg_sum * (1.f - rl);
        out[OFF_REAL + (size_t)b * NN + n] = rl;
        out[OFF_A    + (size_t)b * NN + n] = 0.5f * termA_sum;
    }
}

// ---------------------------------------------------------------------------
extern "C" void kernel_launch(void* const* d_in, const int* in_sizes, int n_in,
                              void* d_out, int out_size, void* d_ws, size_t ws_size,
                              hipStream_t stream) {
    const float* latents   = (const float*)d_in[0];
    const float* realPts   = (const float*)d_in[1];
    const float* predMu    = (const float*)d_in[2];
    const float* predScale = (const float*)d_in[3];
    const float* eps       = (const float*)d_in[4];
    const float* W0 = (const float*)d_in[5];
    const float* b0 = (const float*)d_in[6];
    const float* W1 = (const float*)d_in[7];
    const float* b1 = (const float*)d_in[8];
    const float* W2 = (const float*)d_in[9];
    const float* b2 = (const float*)d_in[10];
    const float* W3 = (const float*)d_in[11];
    const float* b3 = (const float*)d_in[12];
    const float* W4 = (const float*)d_in[13];
    const float* b4 = (const float*)d_in[14];
    const float* Wp = (const float*)d_in[15];
    const float* bp = (const float*)d_in[16];

    float* Wtp = (float*)d_ws;  // 256 KB

    transpose_wp_kernel<<<dim3(256), dim3(256), 0, stream>>>(Wp, Wtp);
    mlp_loss_kernel<<<dim3(BB / RR), dim3(1024), 0, stream>>>(
        latents, eps, realPts, predMu, predScale,
        W0, b0, W1, b1, W2, b2, W3, b3, W4, b4, Wtp, bp, (float*)d_out);
}